// Round 10
// baseline (2560.784 us; speedup 1.0000x reference)
//
#include <hip/hip_runtime.h>
#include <math.h>

#define N_NODES 50000
#define N_EDGES 800000
#define TPB 256

// ---------------- register-blocked f32 GEMM, float4-staged + pipelined ----------------
// out[M,NO] = act( [A1 | A2] @ [W1 ; W2] + bias ),  K = K1 + K2.
// REQUIRES: K1 % 4 == 0, K2 % 4 == 0, row strides % 4 == 0 (16B-aligned float4).
// BM=128, BN=128, BK=16, 256 threads, 8x8 micro-tile (split rows/cols).
// LDS reads per kk: 4 x ds_read_b128 per 64 FMA = 0.5 B/FLOP (the CU balance point;
// round-9's 8x4 tile was 0.75 B/FLOP and measured LDS-read-bound at VALUBusy 40%).
// Split fragments (rows {4tm, 64+4tm}, cols {4tn, 64+4tn}): reads 2-way alias = free.
// BK=16 A-transpose writes: bank = 16*(k4&1) + (l>>2) + 4i -> 32 banks x 2 = free.
// __launch_bounds__(256,3): cap ~168 VGPR (demand ~130; round-9 ballooned to 248
// -> 2 waves/SIMD; round-8's cap of 128 was below demand -> spills. 168 is safe).
template<int ACT>
__global__ __launch_bounds__(256, 3) void gemm_f32(
    const float* __restrict__ A1, int K1, const float* __restrict__ A2, int K2,
    const float* __restrict__ W1, const float* __restrict__ W2,
    const float* __restrict__ bias, float* __restrict__ out, int NO) {
    constexpr int BK = 16;
    __shared__ float sA[BK][132];
    __shared__ float sB[BK][132];
    const int K = K1 + K2;
    const int T = (K + BK - 1) / BK;
    const int tid = threadIdx.x;
    const int tm = tid & 15, tn = tid >> 4;      // 16 x 16 thread grid
    const int row0 = blockIdx.y * 128;
    const int col0 = blockIdx.x * 128;
    float4 vA[2], vB[2];
    float acc[8][8] = {};

    // A tile: 128 rows x 4 float4 (e>>2 = row, e&3 = k4). 4 lanes/row = 64B runs.
    // B tile: 16 k-rows x 32 float4 (e>>5 = kk, e&31 = n4). 512B contiguous runs.
#define LOAD_TILE(t)                                                          \
    {                                                                         \
        _Pragma("unroll")                                                     \
        for (int j = 0; j < 2; ++j) {                                         \
            int e = tid + j * 256;                                            \
            int kg = (t) * BK + (e & 3) * 4;                                  \
            int mg = row0 + (e >> 2);                                         \
            float4 v = {0.f, 0.f, 0.f, 0.f};                                  \
            if (mg < N_NODES) {                                               \
                if (kg < K1)      v = *(const float4*)&A1[(size_t)mg * K1 + kg];        \
                else if (kg < K)  v = *(const float4*)&A2[(size_t)mg * K2 + (kg - K1)]; \
            }                                                                 \
            vA[j] = v;                                                        \
        }                                                                     \
        _Pragma("unroll")                                                     \
        for (int j = 0; j < 2; ++j) {                                         \
            int e = tid + j * 256;                                            \
            int kg = (t) * BK + (e >> 5);                                     \
            int ng = col0 + (e & 31) * 4;                                     \
            float4 v = {0.f, 0.f, 0.f, 0.f};                                  \
            if (kg < K1)      v = *(const float4*)&W1[(size_t)kg * NO + ng];        \
            else if (kg < K)  v = *(const float4*)&W2[(size_t)(kg - K1) * NO + ng]; \
            vB[j] = v;                                                        \
        }                                                                     \
    }

#define STORE_TILE()                                                          \
    {                                                                         \
        _Pragma("unroll")                                                     \
        for (int j = 0; j < 2; ++j) {                                         \
            int e = tid + j * 256;                                            \
            int kk0 = (e & 3) * 4, m = e >> 2;                                \
            sA[kk0 + 0][m] = vA[j].x;                                         \
            sA[kk0 + 1][m] = vA[j].y;                                         \
            sA[kk0 + 2][m] = vA[j].z;                                         \
            sA[kk0 + 3][m] = vA[j].w;                                         \
        }                                                                     \
        _Pragma("unroll")                                                     \
        for (int j = 0; j < 2; ++j) {                                         \
            int e = tid + j * 256;                                            \
            *(float4*)&sB[e >> 5][(e & 31) * 4] = vB[j];                      \
        }                                                                     \
    }

    LOAD_TILE(0);
    STORE_TILE();
    __syncthreads();

    for (int t = 0; t < T; ++t) {
        if (t + 1 < T) LOAD_TILE(t + 1);   // next tile's loads in flight during FMA
#pragma unroll
        for (int kk = 0; kk < BK; ++kk) {
            float4 a0 = *(const float4*)&sA[kk][tm * 4];
            float4 a1 = *(const float4*)&sA[kk][64 + tm * 4];
            float4 b0 = *(const float4*)&sB[kk][tn * 4];
            float4 b1 = *(const float4*)&sB[kk][64 + tn * 4];
            float a[8] = {a0.x, a0.y, a0.z, a0.w, a1.x, a1.y, a1.z, a1.w};
            float b[8] = {b0.x, b0.y, b0.z, b0.w, b1.x, b1.y, b1.z, b1.w};
#pragma unroll
            for (int i = 0; i < 8; ++i)
#pragma unroll
                for (int j2 = 0; j2 < 8; ++j2)
                    acc[i][j2] = fmaf(a[i], b[j2], acc[i][j2]);
        }
        __syncthreads();
        if (t + 1 < T) {
            STORE_TILE();
            __syncthreads();
        }
    }

    const int ng0 = col0 + tn * 4;
    const int ng1 = col0 + 64 + tn * 4;
    float4 bb0 = {0.f, 0.f, 0.f, 0.f}, bb1 = {0.f, 0.f, 0.f, 0.f};
    if (bias) {
        bb0 = *(const float4*)&bias[ng0];
        bb1 = *(const float4*)&bias[ng1];
    }
#pragma unroll
    for (int i = 0; i < 8; ++i) {
        int mg = row0 + ((i < 4) ? (tm * 4 + i) : (64 + tm * 4 + (i - 4)));
        if (mg >= N_NODES) continue;
        float4 v0, v1;
        v0.x = acc[i][0] + bb0.x; v0.y = acc[i][1] + bb0.y;
        v0.z = acc[i][2] + bb0.z; v0.w = acc[i][3] + bb0.w;
        v1.x = acc[i][4] + bb1.x; v1.y = acc[i][5] + bb1.y;
        v1.z = acc[i][6] + bb1.z; v1.w = acc[i][7] + bb1.w;
        if (ACT) {
            v0.x = fmaxf(v0.x, 0.f); v0.y = fmaxf(v0.y, 0.f);
            v0.z = fmaxf(v0.z, 0.f); v0.w = fmaxf(v0.w, 0.f);
            v1.x = fmaxf(v1.x, 0.f); v1.y = fmaxf(v1.y, 0.f);
            v1.z = fmaxf(v1.z, 0.f); v1.w = fmaxf(v1.w, 0.f);
        }
        *(float4*)&out[(size_t)mg * NO + ng0] = v0;
        *(float4*)&out[(size_t)mg * NO + ng1] = v1;
    }
#undef LOAD_TILE
#undef STORE_TILE
}

// ---------------- CSR construction ----------------
__global__ void hist_k(const int* __restrict__ dst, int* __restrict__ deg) {
    int e = blockIdx.x * TPB + threadIdx.x;
    if (e < N_EDGES) atomicAdd(&deg[dst[e]], 1);
}

// single-block exclusive scan over deg -> rowptr (N_NODES+1 entries)
__global__ void scan_k(const int* __restrict__ deg, int* __restrict__ rowptr) {
    __shared__ int part[1024];
    const int tid = threadIdx.x;                     // 1024 threads
    const int CH = (N_NODES + 1023) / 1024;          // 49
    const int base = tid * CH;
    int s = 0;
    for (int i = 0; i < CH; ++i) {
        int idx = base + i;
        if (idx < N_NODES) s += deg[idx];
    }
    part[tid] = s;
    __syncthreads();
    for (int off = 1; off < 1024; off <<= 1) {
        int v = (tid >= off) ? part[tid - off] : 0;
        __syncthreads();
        part[tid] += v;
        __syncthreads();
    }
    int run = (tid == 0) ? 0 : part[tid - 1];
    for (int i = 0; i < CH; ++i) {
        int idx = base + i;
        if (idx < N_NODES) {
            rowptr[idx] = run;
            run += deg[idx];
        }
    }
    if (tid == 1023) rowptr[N_NODES] = run;
}

__global__ void fill_k(const int* __restrict__ src, const int* __restrict__ dst,
                       const int* __restrict__ rowptr, int* __restrict__ fill,
                       int* __restrict__ csr_src) {
    int e = blockIdx.x * TPB + threadIdx.x;
    if (e >= N_EDGES) return;
    int d = dst[e];
    int pos = rowptr[d] + atomicAdd(&fill[d], 1);
    csr_src[pos] = src[e];
}

// ---------------- gather aggregations (no scatter atomics) ----------------
// scalar version (small F, SAGE1's F=20)
template<int F, int BLK>
__global__ void gather_mean(const int* __restrict__ rowptr, const int* __restrict__ csr_src,
                            const float* __restrict__ feat, float* __restrict__ out) {
    int n = blockIdx.x;
    int c = threadIdx.x;
    if (c >= F) return;
    int e0 = rowptr[n], e1 = rowptr[n + 1];
    float acc = 0.f;
    for (int e = e0; e < e1; ++e)
        acc += feat[(size_t)csr_src[e] * F + c];
    out[(size_t)n * F + c] = acc / fmaxf((float)(e1 - e0), 1.0f);
}

// float4 version for F=128: 32 lanes/node, 8 nodes per 256-thread block
__global__ void gather_mean4(const int* __restrict__ rowptr, const int* __restrict__ csr_src,
                             const float4* __restrict__ feat4, float4* __restrict__ out4) {
    int tid = threadIdx.x;
    int n = blockIdx.x * 8 + (tid >> 5);
    int c = tid & 31;
    int e0 = rowptr[n], e1 = rowptr[n + 1];
    float4 acc = {0.f, 0.f, 0.f, 0.f};
    for (int e = e0; e < e1; ++e) {
        float4 v = feat4[(size_t)csr_src[e] * 32 + c];
        acc.x += v.x; acc.y += v.y; acc.z += v.z; acc.w += v.w;
    }
    float inv = 1.0f / fmaxf((float)(e1 - e0), 1.0f);
    acc.x *= inv; acc.y *= inv; acc.z *= inv; acc.w *= inv;
    out4[(size_t)n * 32 + c] = acc;
}

// per-(node,head) attention scores
__global__ void att_scores(const float* __restrict__ h, const float* __restrict__ att_src,
                           const float* __restrict__ att_dst, float* __restrict__ as_,
                           float* __restrict__ ad_) {
    int idx = blockIdx.x * TPB + threadIdx.x;
    if (idx >= N_NODES * 4) return;
    int n = idx >> 2, hd = idx & 3;
    const float* row = h + (size_t)n * 128 + hd * 32;
    float sa = 0.f, sd = 0.f;
    for (int c = 0; c < 32; ++c) {
        float v = row[c];
        sa = fmaf(v, att_src[hd * 32 + c], sa);
        sd = fmaf(v, att_dst[hd * 32 + c], sd);
    }
    as_[idx] = sa;
    ad_[idx] = sd;
}

// fused GAT aggregation, float4: online softmax + weighted gather + ELU
// 32 lanes/node (4 heads x 8 float4-lanes), 8 nodes per 256-thread block
__global__ void gat_gather4(const int* __restrict__ rowptr, const int* __restrict__ csr_src,
                            const float4* __restrict__ h4, const float* __restrict__ as_,
                            const float* __restrict__ ad_, const float* __restrict__ gb,
                            float4* __restrict__ out4) {
    int tid = threadIdx.x;
    int n = blockIdx.x * 8 + (tid >> 5);
    int c = tid & 31;              // float4 index within row; head = c>>3
    int hd = c >> 3;
    int e0 = rowptr[n], e1 = rowptr[n + 1];
    float ad = ad_[n * 4 + hd];
    float m = -INFINITY, s = 0.f;
    float4 acc = {0.f, 0.f, 0.f, 0.f};
    for (int e = e0; e < e1; ++e) {
        int sn = csr_src[e];
        float a = as_[sn * 4 + hd] + ad;
        a = a >= 0.f ? a : 0.2f * a;              // leaky_relu 0.2
        if (a > m) {                               // online softmax rescale
            float sc = __expf(m - a);
            s *= sc; acc.x *= sc; acc.y *= sc; acc.z *= sc; acc.w *= sc;
            m = a;
        }
        float ex = __expf(a - m);
        s += ex;
        float4 v = h4[(size_t)sn * 32 + c];
        acc.x = fmaf(v.x, ex, acc.x); acc.y = fmaf(v.y, ex, acc.y);
        acc.z = fmaf(v.z, ex, acc.z); acc.w = fmaf(v.w, ex, acc.w);
    }
    float inv = 1.0f / (s + 1e-16f);
    float4 r;
    r.x = acc.x * inv + gb[c * 4 + 0];
    r.y = acc.y * inv + gb[c * 4 + 1];
    r.z = acc.z * inv + gb[c * 4 + 2];
    r.w = acc.w * inv + gb[c * 4 + 3];
    r.x = r.x > 0.f ? r.x : expm1f(r.x);
    r.y = r.y > 0.f ? r.y : expm1f(r.y);
    r.z = r.z > 0.f ? r.z : expm1f(r.z);
    r.w = r.w > 0.f ? r.w : expm1f(r.w);
    out4[(size_t)n * 32 + c] = r;
}

// classifier: [N,256] @ [256,5] + b
__global__ void cls_k(const float* __restrict__ h, const float* __restrict__ W,
                      const float* __restrict__ b, float* __restrict__ out) {
    __shared__ float sW[256 * 5];
    for (int i = threadIdx.x; i < 1280; i += TPB) sW[i] = W[i];
    __syncthreads();
    int n = blockIdx.x * TPB + threadIdx.x;
    if (n >= N_NODES) return;
    const float4* row = (const float4*)(h + (size_t)n * 256);
    float acc[5] = {0.f, 0.f, 0.f, 0.f, 0.f};
    for (int k4 = 0; k4 < 64; ++k4) {
        float4 v = row[k4];
        const float* w = &sW[k4 * 4 * 5];
#pragma unroll
        for (int c = 0; c < 5; ++c) acc[c] = fmaf(v.x, w[c], acc[c]);
#pragma unroll
        for (int c = 0; c < 5; ++c) acc[c] = fmaf(v.y, w[5 + c], acc[c]);
#pragma unroll
        for (int c = 0; c < 5; ++c) acc[c] = fmaf(v.z, w[10 + c], acc[c]);
#pragma unroll
        for (int c = 0; c < 5; ++c) acc[c] = fmaf(v.w, w[15 + c], acc[c]);
    }
#pragma unroll
    for (int c = 0; c < 5; ++c) out[(size_t)n * 5 + c] = acc[c] + b[c];
}

extern "C" void kernel_launch(void* const* d_in, const int* in_sizes, int n_in,
                              void* d_out, int out_size, void* d_ws, size_t ws_size,
                              hipStream_t stream) {
    const float* x    = (const float*)d_in[0];
    const int*   ei   = (const int*)d_in[1];
    const float* s1Wl = (const float*)d_in[2];
    const float* s1Wr = (const float*)d_in[3];
    const float* s1b  = (const float*)d_in[4];
    const float* gW   = (const float*)d_in[5];
    const float* gas  = (const float*)d_in[6];
    const float* gad  = (const float*)d_in[7];
    const float* gb   = (const float*)d_in[8];
    const float* s2Wl = (const float*)d_in[9];
    const float* s2Wr = (const float*)d_in[10];
    const float* s2b  = (const float*)d_in[11];
    const float* clsW = (const float*)d_in[12];
    const float* clsb = (const float*)d_in[13];
    float* out = (float*)d_out;
    const int* src = ei;            // edge_index[0]
    const int* dst = ei + N_EDGES;  // edge_index[1]

    // ---- workspace layout (all fully rewritten each call; no stale reads) ----
    float* ws  = (float*)d_ws;
    float* A   = ws;                                  // N*256 (h1, then h3)
    float* C   = A + (size_t)N_NODES * 256;           // N*128 (gat h; later sage2 mean)
    float* D   = C + (size_t)N_NODES * 128;           // N*128 (sage1 mean(20); later gat out/h2)
    float* as_ = D + (size_t)N_NODES * 128;           // N*4
    float* ad_ = as_ + N_NODES * 4;                   // N*4
    int* deg     = (int*)(ad_ + N_NODES * 4);         // N
    int* fill    = deg + N_NODES;                     // N
    int* rowptr  = fill + N_NODES;                    // N+1
    int* csr_src = rowptr + N_NODES + 1;              // E

    const int MB = (N_NODES + 127) / 128;             // 391 row-blocks

    // ---- CSR build ----
    hipMemsetAsync(deg, 0, N_NODES * sizeof(int), stream);
    hipMemsetAsync(fill, 0, N_NODES * sizeof(int), stream);
    hist_k<<<(N_EDGES + TPB - 1) / TPB, TPB, 0, stream>>>(dst, deg);
    scan_k<<<1, 1024, 0, stream>>>(deg, rowptr);
    fill_k<<<(N_EDGES + TPB - 1) / TPB, TPB, 0, stream>>>(src, dst, rowptr, fill, csr_src);

    // ---- SAGE1:  A = relu([mean(x) | x] @ [Wl ; Wr] + b),  K = 20+20 ----
    gather_mean<20, 64><<<N_NODES, 64, 0, stream>>>(rowptr, csr_src, x, D);
    gemm_f32<1><<<dim3(2, MB), 256, 0, stream>>>(D, 20, x, 20, s1Wl, s1Wr, s1b, A, 256);

    // ---- GAT:  C = A @ gW,  K = 256 ----
    gemm_f32<0><<<dim3(1, MB), 256, 0, stream>>>(A, 256, nullptr, 0, gW, nullptr,
                                                 nullptr, C, 128);
    att_scores<<<(N_NODES * 4 + TPB - 1) / TPB, TPB, 0, stream>>>(C, gas, gad, as_, ad_);
    gat_gather4<<<N_NODES / 8, 256, 0, stream>>>(rowptr, csr_src, (const float4*)C,
                                                 as_, ad_, gb, (float4*)D);

    // ---- SAGE2:  A = relu([mean(D) | D] @ [Wl ; Wr] + b),  K = 128+128 ----
    gather_mean4<<<N_NODES / 8, 256, 0, stream>>>(rowptr, csr_src, (const float4*)D,
                                                  (float4*)C);
    gemm_f32<1><<<dim3(2, MB), 256, 0, stream>>>(C, 128, D, 128, s2Wl, s2Wr, s2b, A, 256);

    // ---- classifier ----
    cls_k<<<(N_NODES + TPB - 1) / TPB, TPB, 0, stream>>>(A, clsW, clsb, out);
}

// Round 11
// 745.983 us; speedup vs baseline: 3.4328x; 3.4328x over previous
//
#include <hip/hip_runtime.h>
#include <math.h>

#define N_NODES 50000
#define N_EDGES 800000
#define TPB 256

// ---------------- register-blocked f32 GEMM, 64x64 high-occupancy ----------------
// out[M,NO] = act( [A1 | A2] @ [W1 ; W2] + bias ),  K = K1 + K2.
// REQUIRES: K1 % 4 == 0, K2 % 4 == 0, row strides % 4 == 0 (16B-aligned float4).
// BM=64, BN=64, BK=32, 256 threads, 4x4 micro-tile (acc = 16 VGPR).
// DESIGN RULE (R8/R10 post-mortems): hipcc spills catastrophically under
// launch_bounds caps on staged GEMMs (cap128->spill, cap170->VGPR84+5GB scratch).
// Occupancy must come from LOW NATURAL DEMAND: acc16+stage16+frag8+addr ~ 70-100
// VGPR -> 5 waves/SIMD uncapped. Grid 4x bigger than 128-tiles -> ~12 blocks/CU.
// LDS: sA[32][68] transposed A (column reads: 16 addrs/64 floats, 2-way = free),
//      sB[32][68] (reads broadcast 4 addrs/wave; b128 writes uniform over banks).
// Pipeline: float4 global->reg loads for tile t+1 issued before computing tile t.
template<int ACT>
__global__ __launch_bounds__(256) void gemm_f32(
    const float* __restrict__ A1, int K1, const float* __restrict__ A2, int K2,
    const float* __restrict__ W1, const float* __restrict__ W2,
    const float* __restrict__ bias, float* __restrict__ out, int NO) {
    constexpr int BK = 32;
    __shared__ float sA[BK][68];
    __shared__ float sB[BK][68];
    const int K = K1 + K2;
    const int T = (K + BK - 1) / BK;
    const int tid = threadIdx.x;
    const int tm = tid & 15, tn = tid >> 4;      // 16 x 16 thread grid
    const int row0 = blockIdx.y * 64;
    const int col0 = blockIdx.x * 64;
    float4 vA[2], vB[2];
    float acc[4][4] = {};

    // A tile: 64 rows x 8 float4 (e&7 = k4, e>>3 = row): 8 lanes/row = 128B runs.
    // B tile: 32 k-rows x 16 float4 (e>>4 = kk, e&15 = n4): 256B contiguous runs.
#define LOAD_TILE(t)                                                          \
    {                                                                         \
        _Pragma("unroll")                                                     \
        for (int j = 0; j < 2; ++j) {                                         \
            int e = tid + j * 256;                                            \
            int kg = (t) * BK + (e & 7) * 4;                                  \
            int mg = row0 + (e >> 3);                                         \
            float4 v = {0.f, 0.f, 0.f, 0.f};                                  \
            if (mg < N_NODES) {                                               \
                if (kg < K1)      v = *(const float4*)&A1[(size_t)mg * K1 + kg];        \
                else if (kg < K)  v = *(const float4*)&A2[(size_t)mg * K2 + (kg - K1)]; \
            }                                                                 \
            vA[j] = v;                                                        \
        }                                                                     \
        _Pragma("unroll")                                                     \
        for (int j = 0; j < 2; ++j) {                                         \
            int e = tid + j * 256;                                            \
            int kg = (t) * BK + (e >> 4);                                     \
            int ng = col0 + (e & 15) * 4;                                     \
            float4 v = {0.f, 0.f, 0.f, 0.f};                                  \
            if (kg < K1)      v = *(const float4*)&W1[(size_t)kg * NO + ng];        \
            else if (kg < K)  v = *(const float4*)&W2[(size_t)(kg - K1) * NO + ng]; \
            vB[j] = v;                                                        \
        }                                                                     \
    }

#define STORE_TILE()                                                          \
    {                                                                         \
        _Pragma("unroll")                                                     \
        for (int j = 0; j < 2; ++j) {                                         \
            int e = tid + j * 256;                                            \
            int kk0 = (e & 7) * 4, m = e >> 3;                                \
            sA[kk0 + 0][m] = vA[j].x;                                         \
            sA[kk0 + 1][m] = vA[j].y;                                         \
            sA[kk0 + 2][m] = vA[j].z;                                         \
            sA[kk0 + 3][m] = vA[j].w;                                         \
        }                                                                     \
        _Pragma("unroll")                                                     \
        for (int j = 0; j < 2; ++j) {                                         \
            int e = tid + j * 256;                                            \
            *(float4*)&sB[e >> 4][(e & 15) * 4] = vB[j];                      \
        }                                                                     \
    }

    LOAD_TILE(0);
    STORE_TILE();
    __syncthreads();

    for (int t = 0; t < T; ++t) {
        if (t + 1 < T) LOAD_TILE(t + 1);   // next tile's loads in flight during FMA
#pragma unroll
        for (int kk = 0; kk < BK; ++kk) {
            float4 a0 = *(const float4*)&sA[kk][tm * 4];
            float4 b0 = *(const float4*)&sB[kk][tn * 4];
            float a[4] = {a0.x, a0.y, a0.z, a0.w};
            float b[4] = {b0.x, b0.y, b0.z, b0.w};
#pragma unroll
            for (int i = 0; i < 4; ++i)
#pragma unroll
                for (int j2 = 0; j2 < 4; ++j2)
                    acc[i][j2] = fmaf(a[i], b[j2], acc[i][j2]);
        }
        __syncthreads();
        if (t + 1 < T) {
            STORE_TILE();
            __syncthreads();
        }
    }

    const int ng = col0 + tn * 4;
    float4 bb = {0.f, 0.f, 0.f, 0.f};
    if (bias) bb = *(const float4*)&bias[ng];
#pragma unroll
    for (int i = 0; i < 4; ++i) {
        int mg = row0 + tm * 4 + i;
        if (mg >= N_NODES) continue;
        float4 v;
        v.x = acc[i][0] + bb.x;
        v.y = acc[i][1] + bb.y;
        v.z = acc[i][2] + bb.z;
        v.w = acc[i][3] + bb.w;
        if (ACT) {
            v.x = fmaxf(v.x, 0.f); v.y = fmaxf(v.y, 0.f);
            v.z = fmaxf(v.z, 0.f); v.w = fmaxf(v.w, 0.f);
        }
        *(float4*)&out[(size_t)mg * NO + ng] = v;
    }
#undef LOAD_TILE
#undef STORE_TILE
}

// ---------------- CSR construction ----------------
__global__ void hist_k(const int* __restrict__ dst, int* __restrict__ deg) {
    int e = blockIdx.x * TPB + threadIdx.x;
    if (e < N_EDGES) atomicAdd(&deg[dst[e]], 1);
}

// single-block exclusive scan over deg -> rowptr (N_NODES+1 entries)
__global__ void scan_k(const int* __restrict__ deg, int* __restrict__ rowptr) {
    __shared__ int part[1024];
    const int tid = threadIdx.x;                     // 1024 threads
    const int CH = (N_NODES + 1023) / 1024;          // 49
    const int base = tid * CH;
    int s = 0;
    for (int i = 0; i < CH; ++i) {
        int idx = base + i;
        if (idx < N_NODES) s += deg[idx];
    }
    part[tid] = s;
    __syncthreads();
    for (int off = 1; off < 1024; off <<= 1) {
        int v = (tid >= off) ? part[tid - off] : 0;
        __syncthreads();
        part[tid] += v;
        __syncthreads();
    }
    int run = (tid == 0) ? 0 : part[tid - 1];
    for (int i = 0; i < CH; ++i) {
        int idx = base + i;
        if (idx < N_NODES) {
            rowptr[idx] = run;
            run += deg[idx];
        }
    }
    if (tid == 1023) rowptr[N_NODES] = run;
}

__global__ void fill_k(const int* __restrict__ src, const int* __restrict__ dst,
                       const int* __restrict__ rowptr, int* __restrict__ fill,
                       int* __restrict__ csr_src) {
    int e = blockIdx.x * TPB + threadIdx.x;
    if (e >= N_EDGES) return;
    int d = dst[e];
    int pos = rowptr[d] + atomicAdd(&fill[d], 1);
    csr_src[pos] = src[e];
}

// ---------------- gather aggregations (no scatter atomics) ----------------
// scalar version (small F, SAGE1's F=20)
template<int F, int BLK>
__global__ void gather_mean(const int* __restrict__ rowptr, const int* __restrict__ csr_src,
                            const float* __restrict__ feat, float* __restrict__ out) {
    int n = blockIdx.x;
    int c = threadIdx.x;
    if (c >= F) return;
    int e0 = rowptr[n], e1 = rowptr[n + 1];
    float acc = 0.f;
    for (int e = e0; e < e1; ++e)
        acc += feat[(size_t)csr_src[e] * F + c];
    out[(size_t)n * F + c] = acc / fmaxf((float)(e1 - e0), 1.0f);
}

// float4 version for F=128: 32 lanes/node, 8 nodes per 256-thread block.
// Unroll-by-2: two independent row gathers in flight per iteration.
__global__ void gather_mean4(const int* __restrict__ rowptr, const int* __restrict__ csr_src,
                             const float4* __restrict__ feat4, float4* __restrict__ out4) {
    int tid = threadIdx.x;
    int n = blockIdx.x * 8 + (tid >> 5);
    int c = tid & 31;
    int e0 = rowptr[n], e1 = rowptr[n + 1];
    float4 acc = {0.f, 0.f, 0.f, 0.f};
    int e = e0;
    for (; e + 1 < e1; e += 2) {
        int s0 = csr_src[e], s1 = csr_src[e + 1];
        float4 v0 = feat4[(size_t)s0 * 32 + c];
        float4 v1 = feat4[(size_t)s1 * 32 + c];
        acc.x += v0.x + v1.x; acc.y += v0.y + v1.y;
        acc.z += v0.z + v1.z; acc.w += v0.w + v1.w;
    }
    if (e < e1) {
        float4 v = feat4[(size_t)csr_src[e] * 32 + c];
        acc.x += v.x; acc.y += v.y; acc.z += v.z; acc.w += v.w;
    }
    float inv = 1.0f / fmaxf((float)(e1 - e0), 1.0f);
    acc.x *= inv; acc.y *= inv; acc.z *= inv; acc.w *= inv;
    out4[(size_t)n * 32 + c] = acc;
}

// per-(node,head) attention scores
__global__ void att_scores(const float* __restrict__ h, const float* __restrict__ att_src,
                           const float* __restrict__ att_dst, float* __restrict__ as_,
                           float* __restrict__ ad_) {
    int idx = blockIdx.x * TPB + threadIdx.x;
    if (idx >= N_NODES * 4) return;
    int n = idx >> 2, hd = idx & 3;
    const float* row = h + (size_t)n * 128 + hd * 32;
    float sa = 0.f, sd = 0.f;
    for (int c = 0; c < 32; ++c) {
        float v = row[c];
        sa = fmaf(v, att_src[hd * 32 + c], sa);
        sd = fmaf(v, att_dst[hd * 32 + c], sd);
    }
    as_[idx] = sa;
    ad_[idx] = sd;
}

// fused GAT aggregation, float4: online softmax + weighted gather + ELU
// 32 lanes/node (4 heads x 8 float4-lanes), 8 nodes per 256-thread block
__global__ void gat_gather4(const int* __restrict__ rowptr, const int* __restrict__ csr_src,
                            const float4* __restrict__ h4, const float* __restrict__ as_,
                            const float* __restrict__ ad_, const float* __restrict__ gb,
                            float4* __restrict__ out4) {
    int tid = threadIdx.x;
    int n = blockIdx.x * 8 + (tid >> 5);
    int c = tid & 31;              // float4 index within row; head = c>>3
    int hd = c >> 3;
    int e0 = rowptr[n], e1 = rowptr[n + 1];
    float ad = ad_[n * 4 + hd];
    float m = -INFINITY, s = 0.f;
    float4 acc = {0.f, 0.f, 0.f, 0.f};
    for (int e = e0; e < e1; ++e) {
        int sn = csr_src[e];
        float a = as_[sn * 4 + hd] + ad;
        a = a >= 0.f ? a : 0.2f * a;              // leaky_relu 0.2
        if (a > m) {                               // online softmax rescale
            float sc = __expf(m - a);
            s *= sc; acc.x *= sc; acc.y *= sc; acc.z *= sc; acc.w *= sc;
            m = a;
        }
        float ex = __expf(a - m);
        s += ex;
        float4 v = h4[(size_t)sn * 32 + c];
        acc.x = fmaf(v.x, ex, acc.x); acc.y = fmaf(v.y, ex, acc.y);
        acc.z = fmaf(v.z, ex, acc.z); acc.w = fmaf(v.w, ex, acc.w);
    }
    float inv = 1.0f / (s + 1e-16f);
    float4 r;
    r.x = acc.x * inv + gb[c * 4 + 0];
    r.y = acc.y * inv + gb[c * 4 + 1];
    r.z = acc.z * inv + gb[c * 4 + 2];
    r.w = acc.w * inv + gb[c * 4 + 3];
    r.x = r.x > 0.f ? r.x : expm1f(r.x);
    r.y = r.y > 0.f ? r.y : expm1f(r.y);
    r.z = r.z > 0.f ? r.z : expm1f(r.z);
    r.w = r.w > 0.f ? r.w : expm1f(r.w);
    out4[(size_t)n * 32 + c] = r;
}

// classifier: [N,256] @ [256,5] + b
__global__ void cls_k(const float* __restrict__ h, const float* __restrict__ W,
                      const float* __restrict__ b, float* __restrict__ out) {
    __shared__ float sW[256 * 5];
    for (int i = threadIdx.x; i < 1280; i += TPB) sW[i] = W[i];
    __syncthreads();
    int n = blockIdx.x * TPB + threadIdx.x;
    if (n >= N_NODES) return;
    const float4* row = (const float4*)(h + (size_t)n * 256);
    float acc[5] = {0.f, 0.f, 0.f, 0.f, 0.f};
    for (int k4 = 0; k4 < 64; ++k4) {
        float4 v = row[k4];
        const float* w = &sW[k4 * 4 * 5];
#pragma unroll
        for (int c = 0; c < 5; ++c) acc[c] = fmaf(v.x, w[c], acc[c]);
#pragma unroll
        for (int c = 0; c < 5; ++c) acc[c] = fmaf(v.y, w[5 + c], acc[c]);
#pragma unroll
        for (int c = 0; c < 5; ++c) acc[c] = fmaf(v.z, w[10 + c], acc[c]);
#pragma unroll
        for (int c = 0; c < 5; ++c) acc[c] = fmaf(v.w, w[15 + c], acc[c]);
    }
#pragma unroll
    for (int c = 0; c < 5; ++c) out[(size_t)n * 5 + c] = acc[c] + b[c];
}

extern "C" void kernel_launch(void* const* d_in, const int* in_sizes, int n_in,
                              void* d_out, int out_size, void* d_ws, size_t ws_size,
                              hipStream_t stream) {
    const float* x    = (const float*)d_in[0];
    const int*   ei   = (const int*)d_in[1];
    const float* s1Wl = (const float*)d_in[2];
    const float* s1Wr = (const float*)d_in[3];
    const float* s1b  = (const float*)d_in[4];
    const float* gW   = (const float*)d_in[5];
    const float* gas  = (const float*)d_in[6];
    const float* gad  = (const float*)d_in[7];
    const float* gb   = (const float*)d_in[8];
    const float* s2Wl = (const float*)d_in[9];
    const float* s2Wr = (const float*)d_in[10];
    const float* s2b  = (const float*)d_in[11];
    const float* clsW = (const float*)d_in[12];
    const float* clsb = (const float*)d_in[13];
    float* out = (float*)d_out;
    const int* src = ei;            // edge_index[0]
    const int* dst = ei + N_EDGES;  // edge_index[1]

    // ---- workspace layout (all fully rewritten each call; no stale reads) ----
    float* ws  = (float*)d_ws;
    float* A   = ws;                                  // N*256 (h1, then h3)
    float* C   = A + (size_t)N_NODES * 256;           // N*128 (gat h; later sage2 mean)
    float* D   = C + (size_t)N_NODES * 128;           // N*128 (sage1 mean(20); later gat out/h2)
    float* as_ = D + (size_t)N_NODES * 128;           // N*4
    float* ad_ = as_ + N_NODES * 4;                   // N*4
    int* deg     = (int*)(ad_ + N_NODES * 4);         // N
    int* fill    = deg + N_NODES;                     // N
    int* rowptr  = fill + N_NODES;                    // N+1
    int* csr_src = rowptr + N_NODES + 1;              // E

    const int MB64 = (N_NODES + 63) / 64;             // 782 row-blocks

    // ---- CSR build ----
    hipMemsetAsync(deg, 0, N_NODES * sizeof(int), stream);
    hipMemsetAsync(fill, 0, N_NODES * sizeof(int), stream);
    hist_k<<<(N_EDGES + TPB - 1) / TPB, TPB, 0, stream>>>(dst, deg);
    scan_k<<<1, 1024, 0, stream>>>(deg, rowptr);
    fill_k<<<(N_EDGES + TPB - 1) / TPB, TPB, 0, stream>>>(src, dst, rowptr, fill, csr_src);

    // ---- SAGE1:  A = relu([mean(x) | x] @ [Wl ; Wr] + b),  K = 20+20 ----
    gather_mean<20, 64><<<N_NODES, 64, 0, stream>>>(rowptr, csr_src, x, D);
    gemm_f32<1><<<dim3(4, MB64), 256, 0, stream>>>(D, 20, x, 20, s1Wl, s1Wr, s1b, A, 256);

    // ---- GAT:  C = A @ gW,  K = 256 ----
    gemm_f32<0><<<dim3(2, MB64), 256, 0, stream>>>(A, 256, nullptr, 0, gW, nullptr,
                                                   nullptr, C, 128);
    att_scores<<<(N_NODES * 4 + TPB - 1) / TPB, TPB, 0, stream>>>(C, gas, gad, as_, ad_);
    gat_gather4<<<N_NODES / 8, 256, 0, stream>>>(rowptr, csr_src, (const float4*)C,
                                                 as_, ad_, gb, (float4*)D);

    // ---- SAGE2:  A = relu([mean(D) | D] @ [Wl ; Wr] + b),  K = 128+128 ----
    gather_mean4<<<N_NODES / 8, 256, 0, stream>>>(rowptr, csr_src, (const float4*)D,
                                                  (float4*)C);
    gemm_f32<1><<<dim3(4, MB64), 256, 0, stream>>>(C, 128, D, 128, s2Wl, s2Wr, s2b, A, 256);

    // ---- classifier ----
    cls_k<<<(N_NODES + TPB - 1) / TPB, TPB, 0, stream>>>(A, clsW, clsb, out);
}

// Round 12
// 460.548 us; speedup vs baseline: 5.5603x; 1.6198x over previous
//
#include <hip/hip_runtime.h>
#include <math.h>

#define N_NODES 50000
#define N_EDGES 800000
#define TPB 256

typedef short s16x8 __attribute__((ext_vector_type(8)));
typedef float f32x4 __attribute__((ext_vector_type(4)));

__device__ __forceinline__ unsigned short f2bf(float f) {
    unsigned u = __float_as_uint(f);
    u += 0x7fffu + ((u >> 16) & 1u);          // round-to-nearest-even
    return (unsigned short)(u >> 16);
}

// ---------------- weight pre-transpose + bf16 cast ----------------
// Wt[n][k] = bf16( k<K1 ? W1[k][n] : k<K1+K2 ? W2[k-K1][n] : 0 ), k < Kp.
// Folds the [W1;W2] concat and pads K to Kp (multiple of 32). Tiny, L2-resident.
__global__ void wt_k(const float* __restrict__ W1, int K1,
                     const float* __restrict__ W2, int K2,
                     int NO, int Kp, unsigned short* __restrict__ Wt) {
    int idx = blockIdx.x * TPB + threadIdx.x;
    if (idx >= NO * Kp) return;
    int n = idx / Kp, k = idx - n * Kp;
    float v = 0.f;
    if (k < K1) v = W1[(size_t)k * NO + n];
    else if (k < K1 + K2) v = W2[(size_t)(k - K1) * NO + n];
    Wt[idx] = f2bf(v);
}

// ---------------- bf16 MFMA GEMM ----------------
// out[M,NO] = act( [A1 | A2] @ W + bias ), W given pre-transposed bf16 [NO][Kp].
// A1,A2 f32 (K1,K2 cols, K1%4==0), converted to bf16 during staging.
// 256 threads = 4 waves (2x2); block tile 128x128; BK=32; wave tile 64x64
// = 4x4 MFMA 16x16x32 fragments. f32 accumulate.
// Fragment layout (verified m89/m91): A-frag lane l holds A[l&15][(l>>4)*8+j];
// B-frag holds B[(l>>4)*8+j][l&15] = Wt[col=l&15][k..]; C/D col=l&15,
// row=(l>>4)*4+reg. LDS rows padded to 40 ushorts (80 B = 16B-aligned,
// bank step 20 dwords -> 2-way alias = free).
// NO launch_bounds (R8/R10: caps => catastrophic spills).
template<int ACT>
__global__ void gemm_mfma(const float* __restrict__ A1, int K1,
                          const float* __restrict__ A2, int K2,
                          const unsigned short* __restrict__ Wt, int Kp,
                          const float* __restrict__ bias,
                          float* __restrict__ out, int NO) {
    constexpr int BM = 128, BK = 32, LDP = 40;
    __shared__ unsigned short sA[BM * LDP];
    __shared__ unsigned short sB[128 * LDP];
    const int K = K1 + K2;
    const int T = Kp / BK;
    const int tid = threadIdx.x;
    const int lane = tid & 63, wid = tid >> 6;
    const int wr = wid >> 1, wc = wid & 1;
    const int row0 = blockIdx.y * BM, col0 = blockIdx.x * 128;
    const int l15 = lane & 15, l4 = lane >> 4;
    f32x4 acc[4][4] = {};

    for (int t = 0; t < T; ++t) {
        __syncthreads();                       // LDS write-after-read guard
        // stage A: 128 rows x 32 k (f32 float4 -> 4x bf16, 8B LDS store)
#pragma unroll
        for (int j = 0; j < 4; ++j) {
            int e = tid + j * 256;
            int r = e >> 3, k4 = e & 7;
            int kg = t * BK + k4 * 4, mg = row0 + r;
            float4 v = {0.f, 0.f, 0.f, 0.f};
            if (mg < N_NODES) {
                if (kg < K1)     v = *(const float4*)&A1[(size_t)mg * K1 + kg];
                else if (kg < K) v = *(const float4*)&A2[(size_t)mg * K2 + (kg - K1)];
            }
            ushort4 b;
            b.x = f2bf(v.x); b.y = f2bf(v.y); b.z = f2bf(v.z); b.w = f2bf(v.w);
            *(ushort4*)&sA[r * LDP + k4 * 4] = b;
        }
        // stage B: 128 n-rows x 32 k bf16 (16B copies from Wt[n][k])
#pragma unroll
        for (int j = 0; j < 2; ++j) {
            int e = tid + j * 256;
            int n = e >> 2, k8 = e & 3;
            int4 v = *(const int4*)&Wt[(size_t)(col0 + n) * Kp + t * BK + k8 * 8];
            *(int4*)&sB[n * LDP + k8 * 8] = v;
        }
        __syncthreads();
        s16x8 af[4], bfr[4];
#pragma unroll
        for (int i = 0; i < 4; ++i) {
            af[i]  = *(const s16x8*)&sA[(wr * 64 + i * 16 + l15) * LDP + l4 * 8];
            bfr[i] = *(const s16x8*)&sB[(wc * 64 + i * 16 + l15) * LDP + l4 * 8];
        }
#pragma unroll
        for (int mi = 0; mi < 4; ++mi)
#pragma unroll
            for (int ni = 0; ni < 4; ++ni)
                acc[mi][ni] = __builtin_amdgcn_mfma_f32_16x16x32_bf16(
                    af[mi], bfr[ni], acc[mi][ni], 0, 0, 0);
    }
#pragma unroll
    for (int mi = 0; mi < 4; ++mi) {
#pragma unroll
        for (int ni = 0; ni < 4; ++ni) {
            int col = col0 + wc * 64 + ni * 16 + l15;
            float bb = bias ? bias[col] : 0.f;
#pragma unroll
            for (int r = 0; r < 4; ++r) {
                int row = row0 + wr * 64 + mi * 16 + l4 * 4 + r;
                if (row < N_NODES) {
                    float v = acc[mi][ni][r] + bb;
                    if (ACT) v = fmaxf(v, 0.f);
                    out[(size_t)row * NO + col] = v;
                }
            }
        }
    }
}

// ---------------- CSR construction ----------------
__global__ void hist_k(const int* __restrict__ dst, int* __restrict__ deg) {
    int e = blockIdx.x * TPB + threadIdx.x;
    if (e < N_EDGES) atomicAdd(&deg[dst[e]], 1);
}

__global__ void scan_k(const int* __restrict__ deg, int* __restrict__ rowptr) {
    __shared__ int part[1024];
    const int tid = threadIdx.x;                     // 1024 threads
    const int CH = (N_NODES + 1023) / 1024;          // 49
    const int base = tid * CH;
    int s = 0;
    for (int i = 0; i < CH; ++i) {
        int idx = base + i;
        if (idx < N_NODES) s += deg[idx];
    }
    part[tid] = s;
    __syncthreads();
    for (int off = 1; off < 1024; off <<= 1) {
        int v = (tid >= off) ? part[tid - off] : 0;
        __syncthreads();
        part[tid] += v;
        __syncthreads();
    }
    int run = (tid == 0) ? 0 : part[tid - 1];
    for (int i = 0; i < CH; ++i) {
        int idx = base + i;
        if (idx < N_NODES) {
            rowptr[idx] = run;
            run += deg[idx];
        }
    }
    if (tid == 1023) rowptr[N_NODES] = run;
}

__global__ void fill_k(const int* __restrict__ src, const int* __restrict__ dst,
                       const int* __restrict__ rowptr, int* __restrict__ fill,
                       int* __restrict__ csr_src) {
    int e = blockIdx.x * TPB + threadIdx.x;
    if (e >= N_EDGES) return;
    int d = dst[e];
    int pos = rowptr[d] + atomicAdd(&fill[d], 1);
    csr_src[pos] = src[e];
}

// ---------------- gather aggregations ----------------
template<int F, int BLK>
__global__ void gather_mean(const int* __restrict__ rowptr, const int* __restrict__ csr_src,
                            const float* __restrict__ feat, float* __restrict__ out) {
    int n = blockIdx.x;
    int c = threadIdx.x;
    if (c >= F) return;
    int e0 = rowptr[n], e1 = rowptr[n + 1];
    float acc = 0.f;
    for (int e = e0; e < e1; ++e)
        acc += feat[(size_t)csr_src[e] * F + c];
    out[(size_t)n * F + c] = acc / fmaxf((float)(e1 - e0), 1.0f);
}

__global__ void gather_mean4(const int* __restrict__ rowptr, const int* __restrict__ csr_src,
                             const float4* __restrict__ feat4, float4* __restrict__ out4) {
    int tid = threadIdx.x;
    int n = blockIdx.x * 8 + (tid >> 5);
    int c = tid & 31;
    int e0 = rowptr[n], e1 = rowptr[n + 1];
    float4 acc = {0.f, 0.f, 0.f, 0.f};
    int e = e0;
    for (; e + 1 < e1; e += 2) {
        int s0 = csr_src[e], s1 = csr_src[e + 1];
        float4 v0 = feat4[(size_t)s0 * 32 + c];
        float4 v1 = feat4[(size_t)s1 * 32 + c];
        acc.x += v0.x + v1.x; acc.y += v0.y + v1.y;
        acc.z += v0.z + v1.z; acc.w += v0.w + v1.w;
    }
    if (e < e1) {
        float4 v = feat4[(size_t)csr_src[e] * 32 + c];
        acc.x += v.x; acc.y += v.y; acc.z += v.z; acc.w += v.w;
    }
    float inv = 1.0f / fmaxf((float)(e1 - e0), 1.0f);
    acc.x *= inv; acc.y *= inv; acc.z *= inv; acc.w *= inv;
    out4[(size_t)n * 32 + c] = acc;
}

// per-(node,head) attention scores
__global__ void att_scores(const float* __restrict__ h, const float* __restrict__ att_src,
                           const float* __restrict__ att_dst, float* __restrict__ as_,
                           float* __restrict__ ad_) {
    int idx = blockIdx.x * TPB + threadIdx.x;
    if (idx >= N_NODES * 4) return;
    int n = idx >> 2, hd = idx & 3;
    const float* row = h + (size_t)n * 128 + hd * 32;
    float sa = 0.f, sd = 0.f;
    for (int c = 0; c < 32; ++c) {
        float v = row[c];
        sa = fmaf(v, att_src[hd * 32 + c], sa);
        sd = fmaf(v, att_dst[hd * 32 + c], sd);
    }
    as_[idx] = sa;
    ad_[idx] = sd;
}

// fused GAT aggregation: online softmax + weighted gather + ELU
__global__ void gat_gather4(const int* __restrict__ rowptr, const int* __restrict__ csr_src,
                            const float4* __restrict__ h4, const float* __restrict__ as_,
                            const float* __restrict__ ad_, const float* __restrict__ gb,
                            float4* __restrict__ out4) {
    int tid = threadIdx.x;
    int n = blockIdx.x * 8 + (tid >> 5);
    int c = tid & 31;              // float4 index within row; head = c>>3
    int hd = c >> 3;
    int e0 = rowptr[n], e1 = rowptr[n + 1];
    float ad = ad_[n * 4 + hd];
    float m = -INFINITY, s = 0.f;
    float4 acc = {0.f, 0.f, 0.f, 0.f};
    for (int e = e0; e < e1; ++e) {
        int sn = csr_src[e];
        float a = as_[sn * 4 + hd] + ad;
        a = a >= 0.f ? a : 0.2f * a;              // leaky_relu 0.2
        if (a > m) {                               // online softmax rescale
            float sc = __expf(m - a);
            s *= sc; acc.x *= sc; acc.y *= sc; acc.z *= sc; acc.w *= sc;
            m = a;
        }
        float ex = __expf(a - m);
        s += ex;
        float4 v = h4[(size_t)sn * 32 + c];
        acc.x = fmaf(v.x, ex, acc.x); acc.y = fmaf(v.y, ex, acc.y);
        acc.z = fmaf(v.z, ex, acc.z); acc.w = fmaf(v.w, ex, acc.w);
    }
    float inv = 1.0f / (s + 1e-16f);
    float4 r;
    r.x = acc.x * inv + gb[c * 4 + 0];
    r.y = acc.y * inv + gb[c * 4 + 1];
    r.z = acc.z * inv + gb[c * 4 + 2];
    r.w = acc.w * inv + gb[c * 4 + 3];
    r.x = r.x > 0.f ? r.x : expm1f(r.x);
    r.y = r.y > 0.f ? r.y : expm1f(r.y);
    r.z = r.z > 0.f ? r.z : expm1f(r.z);
    r.w = r.w > 0.f ? r.w : expm1f(r.w);
    out4[(size_t)n * 32 + c] = r;
}

// classifier: [N,256] @ [256,5] + b   (f32)
__global__ void cls_k(const float* __restrict__ h, const float* __restrict__ W,
                      const float* __restrict__ b, float* __restrict__ out) {
    __shared__ float sW[256 * 5];
    for (int i = threadIdx.x; i < 1280; i += TPB) sW[i] = W[i];
    __syncthreads();
    int n = blockIdx.x * TPB + threadIdx.x;
    if (n >= N_NODES) return;
    const float4* row = (const float4*)(h + (size_t)n * 256);
    float acc[5] = {0.f, 0.f, 0.f, 0.f, 0.f};
    for (int k4 = 0; k4 < 64; ++k4) {
        float4 v = row[k4];
        const float* w = &sW[k4 * 4 * 5];
#pragma unroll
        for (int c = 0; c < 5; ++c) acc[c] = fmaf(v.x, w[c], acc[c]);
#pragma unroll
        for (int c = 0; c < 5; ++c) acc[c] = fmaf(v.y, w[5 + c], acc[c]);
#pragma unroll
        for (int c = 0; c < 5; ++c) acc[c] = fmaf(v.z, w[10 + c], acc[c]);
#pragma unroll
        for (int c = 0; c < 5; ++c) acc[c] = fmaf(v.w, w[15 + c], acc[c]);
    }
#pragma unroll
    for (int c = 0; c < 5; ++c) out[(size_t)n * 5 + c] = acc[c] + b[c];
}

extern "C" void kernel_launch(void* const* d_in, const int* in_sizes, int n_in,
                              void* d_out, int out_size, void* d_ws, size_t ws_size,
                              hipStream_t stream) {
    const float* x    = (const float*)d_in[0];
    const int*   ei   = (const int*)d_in[1];
    const float* s1Wl = (const float*)d_in[2];
    const float* s1Wr = (const float*)d_in[3];
    const float* s1b  = (const float*)d_in[4];
    const float* gW   = (const float*)d_in[5];
    const float* gas  = (const float*)d_in[6];
    const float* gad  = (const float*)d_in[7];
    const float* gb   = (const float*)d_in[8];
    const float* s2Wl = (const float*)d_in[9];
    const float* s2Wr = (const float*)d_in[10];
    const float* s2b  = (const float*)d_in[11];
    const float* clsW = (const float*)d_in[12];
    const float* clsb = (const float*)d_in[13];
    float* out = (float*)d_out;
    const int* src = ei;            // edge_index[0]
    const int* dst = ei + N_EDGES;  // edge_index[1]

    // ---- workspace layout (all fully rewritten each call; no stale reads) ----
    float* ws  = (float*)d_ws;
    float* A   = ws;                                  // N*256 (h1, then h3)
    float* C   = A + (size_t)N_NODES * 256;           // N*128 (gat h; later sage2 mean)
    float* D   = C + (size_t)N_NODES * 128;           // N*128 (sage1 mean(20); later gat out/h2)
    float* as_ = D + (size_t)N_NODES * 128;           // N*4
    float* ad_ = as_ + N_NODES * 4;                   // N*4
    int* deg     = (int*)(ad_ + N_NODES * 4);         // N
    int* fill    = deg + N_NODES;                     // N
    int* rowptr  = fill + N_NODES;                    // N+1
    int* csr_src = rowptr + N_NODES + 1;              // E
    unsigned short* Wt1 = (unsigned short*)(csr_src + N_EDGES);  // 256*64
    unsigned short* Wt2 = Wt1 + 256 * 64;                        // 128*256
    unsigned short* Wt3 = Wt2 + 128 * 256;                       // 256*256

    const int MB = (N_NODES + 127) / 128;             // 391 row-blocks

    // ---- weight transpose + bf16 cast (tiny) ----
    wt_k<<<(256 * 64 + TPB - 1) / TPB, TPB, 0, stream>>>(s1Wl, 20, s1Wr, 20, 256, 64, Wt1);
    wt_k<<<(128 * 256 + TPB - 1) / TPB, TPB, 0, stream>>>(gW, 256, nullptr, 0, 128, 256, Wt2);
    wt_k<<<(256 * 256 + TPB - 1) / TPB, TPB, 0, stream>>>(s2Wl, 128, s2Wr, 128, 256, 256, Wt3);

    // ---- CSR build ----
    hipMemsetAsync(deg, 0, N_NODES * sizeof(int), stream);
    hipMemsetAsync(fill, 0, N_NODES * sizeof(int), stream);
    hist_k<<<(N_EDGES + TPB - 1) / TPB, TPB, 0, stream>>>(dst, deg);
    scan_k<<<1, 1024, 0, stream>>>(deg, rowptr);
    fill_k<<<(N_EDGES + TPB - 1) / TPB, TPB, 0, stream>>>(src, dst, rowptr, fill, csr_src);

    // ---- SAGE1:  A = relu([mean(x) | x] @ [Wl ; Wr] + b),  K=40 (Kp=64) ----
    gather_mean<20, 64><<<N_NODES, 64, 0, stream>>>(rowptr, csr_src, x, D);
    gemm_mfma<1><<<dim3(2, MB), 256, 0, stream>>>(D, 20, x, 20, Wt1, 64, s1b, A, 256);

    // ---- GAT:  C = A @ gW,  K=256 ----
    gemm_mfma<0><<<dim3(1, MB), 256, 0, stream>>>(A, 256, nullptr, 0, Wt2, 256,
                                                  nullptr, C, 128);
    att_scores<<<(N_NODES * 4 + TPB - 1) / TPB, TPB, 0, stream>>>(C, gas, gad, as_, ad_);
    gat_gather4<<<N_NODES / 8, 256, 0, stream>>>(rowptr, csr_src, (const float4*)C,
                                                 as_, ad_, gb, (float4*)D);

    // ---- SAGE2:  A = relu([mean(D) | D] @ [Wl ; Wr] + b),  K=256 ----
    gather_mean4<<<N_NODES / 8, 256, 0, stream>>>(rowptr, csr_src, (const float4*)D,
                                                  (float4*)C);
    gemm_mfma<1><<<dim3(2, MB), 256, 0, stream>>>(C, 128, D, 128, Wt3, 256, s2b, A, 256);

    // ---- classifier ----
    cls_k<<<(N_NODES + TPB - 1) / TPB, TPB, 0, stream>>>(A, clsW, clsb, out);
}

// Round 13
// 384.005 us; speedup vs baseline: 6.6686x; 1.1993x over previous
//
#include <hip/hip_runtime.h>
#include <math.h>

#define N_NODES 50000
#define N_EDGES 800000
#define TPB 256
#define NCHUNK ((N_NODES + 255) / 256)   // 196 scan blocks

typedef short s16x8 __attribute__((ext_vector_type(8)));
typedef float f32x4 __attribute__((ext_vector_type(4)));

__device__ __forceinline__ unsigned short f2bf(float f) {
    unsigned u = __float_as_uint(f);
    u += 0x7fffu + ((u >> 16) & 1u);          // round-to-nearest-even
    return (unsigned short)(u >> 16);
}

// ---------------- weight pre-transpose + bf16 cast ----------------
// Wt[n][k] = bf16( k<K1 ? W1[k][n] : k<K1+K2 ? W2[k-K1][n] : 0 ), k < Kp.
__global__ void wt_k(const float* __restrict__ W1, int K1,
                     const float* __restrict__ W2, int K2,
                     int NO, int Kp, unsigned short* __restrict__ Wt) {
    int idx = blockIdx.x * TPB + threadIdx.x;
    if (idx >= NO * Kp) return;
    int n = idx / Kp, k = idx - n * Kp;
    float v = 0.f;
    if (k < K1) v = W1[(size_t)k * NO + n];
    else if (k < K1 + K2) v = W2[(size_t)(k - K1) * NO + n];
    Wt[idx] = f2bf(v);
}

// ---------------- bf16 MFMA GEMM (unchanged from R12: 460us, MfmaUtil>0) ----------------
template<int ACT>
__global__ void gemm_mfma(const float* __restrict__ A1, int K1,
                          const float* __restrict__ A2, int K2,
                          const unsigned short* __restrict__ Wt, int Kp,
                          const float* __restrict__ bias,
                          float* __restrict__ out, int NO) {
    constexpr int BM = 128, BK = 32, LDP = 40;
    __shared__ unsigned short sA[BM * LDP];
    __shared__ unsigned short sB[128 * LDP];
    const int K = K1 + K2;
    const int T = Kp / BK;
    const int tid = threadIdx.x;
    const int lane = tid & 63, wid = tid >> 6;
    const int wr = wid >> 1, wc = wid & 1;
    const int row0 = blockIdx.y * BM, col0 = blockIdx.x * 128;
    const int l15 = lane & 15, l4 = lane >> 4;
    f32x4 acc[4][4] = {};

    for (int t = 0; t < T; ++t) {
        __syncthreads();                       // LDS write-after-read guard
#pragma unroll
        for (int j = 0; j < 4; ++j) {
            int e = tid + j * 256;
            int r = e >> 3, k4 = e & 7;
            int kg = t * BK + k4 * 4, mg = row0 + r;
            float4 v = {0.f, 0.f, 0.f, 0.f};
            if (mg < N_NODES) {
                if (kg < K1)     v = *(const float4*)&A1[(size_t)mg * K1 + kg];
                else if (kg < K) v = *(const float4*)&A2[(size_t)mg * K2 + (kg - K1)];
            }
            ushort4 b;
            b.x = f2bf(v.x); b.y = f2bf(v.y); b.z = f2bf(v.z); b.w = f2bf(v.w);
            *(ushort4*)&sA[r * LDP + k4 * 4] = b;
        }
#pragma unroll
        for (int j = 0; j < 2; ++j) {
            int e = tid + j * 256;
            int n = e >> 2, k8 = e & 3;
            int4 v = *(const int4*)&Wt[(size_t)(col0 + n) * Kp + t * BK + k8 * 8];
            *(int4*)&sB[n * LDP + k8 * 8] = v;
        }
        __syncthreads();
        s16x8 af[4], bfr[4];
#pragma unroll
        for (int i = 0; i < 4; ++i) {
            af[i]  = *(const s16x8*)&sA[(wr * 64 + i * 16 + l15) * LDP + l4 * 8];
            bfr[i] = *(const s16x8*)&sB[(wc * 64 + i * 16 + l15) * LDP + l4 * 8];
        }
#pragma unroll
        for (int mi = 0; mi < 4; ++mi)
#pragma unroll
            for (int ni = 0; ni < 4; ++ni)
                acc[mi][ni] = __builtin_amdgcn_mfma_f32_16x16x32_bf16(
                    af[mi], bfr[ni], acc[mi][ni], 0, 0, 0);
    }
#pragma unroll
    for (int mi = 0; mi < 4; ++mi) {
#pragma unroll
        for (int ni = 0; ni < 4; ++ni) {
            int col = col0 + wc * 64 + ni * 16 + l15;
            float bb = bias ? bias[col] : 0.f;
#pragma unroll
            for (int r = 0; r < 4; ++r) {
                int row = row0 + wr * 64 + mi * 16 + l4 * 4 + r;
                if (row < N_NODES) {
                    float v = acc[mi][ni][r] + bb;
                    if (ACT) v = fmaxf(v, 0.f);
                    out[(size_t)row * NO + col] = v;
                }
            }
        }
    }
}

// ---------------- CSR construction ----------------
__global__ void hist_k(const int* __restrict__ dst, int* __restrict__ deg) {
    int e = blockIdx.x * TPB + threadIdx.x;
    if (e < N_EDGES) atomicAdd(&deg[dst[e]], 1);
}

// hierarchical scan (R12 post-mortem: single-block scan_k was 93us = 20% of total).
// scan1: per-block exclusive scan (coalesced) + block totals
__global__ void scan1_k(const int* __restrict__ deg, int* __restrict__ rowptr,
                        int* __restrict__ bsum) {
    __shared__ int tmp[256];
    int tid = threadIdx.x;
    int idx = blockIdx.x * 256 + tid;
    int v = (idx < N_NODES) ? deg[idx] : 0;
    tmp[tid] = v;
    __syncthreads();
    for (int off = 1; off < 256; off <<= 1) {
        int t = (tid >= off) ? tmp[tid - off] : 0;
        __syncthreads();
        tmp[tid] += t;
        __syncthreads();
    }
    if (idx < N_NODES) rowptr[idx] = tmp[tid] - v;   // exclusive within block
    if (tid == 255) bsum[blockIdx.x] = tmp[255];
}

// scan2: one block scans the NCHUNK (<=256) block sums in place (-> exclusive)
__global__ void scan2_k(int* __restrict__ bsum) {
    __shared__ int tmp[256];
    int tid = threadIdx.x;
    int v = (tid < NCHUNK) ? bsum[tid] : 0;
    tmp[tid] = v;
    __syncthreads();
    for (int off = 1; off < 256; off <<= 1) {
        int t = (tid >= off) ? tmp[tid - off] : 0;
        __syncthreads();
        tmp[tid] += t;
        __syncthreads();
    }
    if (tid < NCHUNK) bsum[tid] = tmp[tid] - v;
}

// scan3: add block offsets; rowptr[N] = E (total degree is known)
__global__ void scan3_k(int* __restrict__ rowptr, const int* __restrict__ bsum) {
    int idx = blockIdx.x * 256 + threadIdx.x;
    if (idx < N_NODES) rowptr[idx] += bsum[blockIdx.x];
    if (idx == 0) rowptr[N_NODES] = N_EDGES;
}

// fill: rank via atomicSub on deg (deg is dead after scan; becomes 0 after this,
// which is exactly the state hist_k needs next call -> no fill array, no memset...
// NOTE: deg is re-zeroed by memset each call anyway for determinism.)
__global__ void fill_k(const int* __restrict__ src, const int* __restrict__ dst,
                       const int* __restrict__ rowptr, int* __restrict__ deg,
                       int* __restrict__ csr_src) {
    int e = blockIdx.x * TPB + threadIdx.x;
    if (e >= N_EDGES) return;
    int d = dst[e];
    int r = atomicSub(&deg[d], 1) - 1;
    csr_src[rowptr[d] + r] = src[e];
}

// ---------------- gather aggregations ----------------
template<int F, int BLK>
__global__ void gather_mean(const int* __restrict__ rowptr, const int* __restrict__ csr_src,
                            const float* __restrict__ feat, float* __restrict__ out) {
    int n = blockIdx.x;
    int c = threadIdx.x;
    if (c >= F) return;
    int e0 = rowptr[n], e1 = rowptr[n + 1];
    float acc = 0.f;
    for (int e = e0; e < e1; ++e)
        acc += feat[(size_t)csr_src[e] * F + c];
    out[(size_t)n * F + c] = acc / fmaxf((float)(e1 - e0), 1.0f);
}

__global__ void gather_mean4(const int* __restrict__ rowptr, const int* __restrict__ csr_src,
                             const float4* __restrict__ feat4, float4* __restrict__ out4) {
    int tid = threadIdx.x;
    int n = blockIdx.x * 8 + (tid >> 5);
    int c = tid & 31;
    int e0 = rowptr[n], e1 = rowptr[n + 1];
    float4 acc = {0.f, 0.f, 0.f, 0.f};
    int e = e0;
    for (; e + 1 < e1; e += 2) {
        int s0 = csr_src[e], s1 = csr_src[e + 1];
        float4 v0 = feat4[(size_t)s0 * 32 + c];
        float4 v1 = feat4[(size_t)s1 * 32 + c];
        acc.x += v0.x + v1.x; acc.y += v0.y + v1.y;
        acc.z += v0.z + v1.z; acc.w += v0.w + v1.w;
    }
    if (e < e1) {
        float4 v = feat4[(size_t)csr_src[e] * 32 + c];
        acc.x += v.x; acc.y += v.y; acc.z += v.z; acc.w += v.w;
    }
    float inv = 1.0f / fmaxf((float)(e1 - e0), 1.0f);
    acc.x *= inv; acc.y *= inv; acc.z *= inv; acc.w *= inv;
    out4[(size_t)n * 32 + c] = acc;
}

// per-(node,head) attention scores
__global__ void att_scores(const float* __restrict__ h, const float* __restrict__ att_src,
                           const float* __restrict__ att_dst, float* __restrict__ as_,
                           float* __restrict__ ad_) {
    int idx = blockIdx.x * TPB + threadIdx.x;
    if (idx >= N_NODES * 4) return;
    int n = idx >> 2, hd = idx & 3;
    const float* row = h + (size_t)n * 128 + hd * 32;
    float sa = 0.f, sd = 0.f;
    for (int c = 0; c < 32; ++c) {
        float v = row[c];
        sa = fmaf(v, att_src[hd * 32 + c], sa);
        sd = fmaf(v, att_dst[hd * 32 + c], sd);
    }
    as_[idx] = sa;
    ad_[idx] = sd;
}

// fused GAT aggregation: online softmax + weighted gather + ELU
__global__ void gat_gather4(const int* __restrict__ rowptr, const int* __restrict__ csr_src,
                            const float4* __restrict__ h4, const float* __restrict__ as_,
                            const float* __restrict__ ad_, const float* __restrict__ gb,
                            float4* __restrict__ out4) {
    int tid = threadIdx.x;
    int n = blockIdx.x * 8 + (tid >> 5);
    int c = tid & 31;              // float4 index within row; head = c>>3
    int hd = c >> 3;
    int e0 = rowptr[n], e1 = rowptr[n + 1];
    float ad = ad_[n * 4 + hd];
    float m = -INFINITY, s = 0.f;
    float4 acc = {0.f, 0.f, 0.f, 0.f};
    for (int e = e0; e < e1; ++e) {
        int sn = csr_src[e];
        float a = as_[sn * 4 + hd] + ad;
        a = a >= 0.f ? a : 0.2f * a;              // leaky_relu 0.2
        if (a > m) {                               // online softmax rescale
            float sc = __expf(m - a);
            s *= sc; acc.x *= sc; acc.y *= sc; acc.z *= sc; acc.w *= sc;
            m = a;
        }
        float ex = __expf(a - m);
        s += ex;
        float4 v = h4[(size_t)sn * 32 + c];
        acc.x = fmaf(v.x, ex, acc.x); acc.y = fmaf(v.y, ex, acc.y);
        acc.z = fmaf(v.z, ex, acc.z); acc.w = fmaf(v.w, ex, acc.w);
    }
    float inv = 1.0f / (s + 1e-16f);
    float4 r;
    r.x = acc.x * inv + gb[c * 4 + 0];
    r.y = acc.y * inv + gb[c * 4 + 1];
    r.z = acc.z * inv + gb[c * 4 + 2];
    r.w = acc.w * inv + gb[c * 4 + 3];
    r.x = r.x > 0.f ? r.x : expm1f(r.x);
    r.y = r.y > 0.f ? r.y : expm1f(r.y);
    r.z = r.z > 0.f ? r.z : expm1f(r.z);
    r.w = r.w > 0.f ? r.w : expm1f(r.w);
    out4[(size_t)n * 32 + c] = r;
}

// classifier: [N,256] @ [256,5] + b   (f32)
__global__ void cls_k(const float* __restrict__ h, const float* __restrict__ W,
                      const float* __restrict__ b, float* __restrict__ out) {
    __shared__ float sW[256 * 5];
    for (int i = threadIdx.x; i < 1280; i += TPB) sW[i] = W[i];
    __syncthreads();
    int n = blockIdx.x * TPB + threadIdx.x;
    if (n >= N_NODES) return;
    const float4* row = (const float4*)(h + (size_t)n * 256);
    float acc[5] = {0.f, 0.f, 0.f, 0.f, 0.f};
    for (int k4 = 0; k4 < 64; ++k4) {
        float4 v = row[k4];
        const float* w = &sW[k4 * 4 * 5];
#pragma unroll
        for (int c = 0; c < 5; ++c) acc[c] = fmaf(v.x, w[c], acc[c]);
#pragma unroll
        for (int c = 0; c < 5; ++c) acc[c] = fmaf(v.y, w[5 + c], acc[c]);
#pragma unroll
        for (int c = 0; c < 5; ++c) acc[c] = fmaf(v.z, w[10 + c], acc[c]);
#pragma unroll
        for (int c = 0; c < 5; ++c) acc[c] = fmaf(v.w, w[15 + c], acc[c]);
    }
#pragma unroll
    for (int c = 0; c < 5; ++c) out[(size_t)n * 5 + c] = acc[c] + b[c];
}

extern "C" void kernel_launch(void* const* d_in, const int* in_sizes, int n_in,
                              void* d_out, int out_size, void* d_ws, size_t ws_size,
                              hipStream_t stream) {
    const float* x    = (const float*)d_in[0];
    const int*   ei   = (const int*)d_in[1];
    const float* s1Wl = (const float*)d_in[2];
    const float* s1Wr = (const float*)d_in[3];
    const float* s1b  = (const float*)d_in[4];
    const float* gW   = (const float*)d_in[5];
    const float* gas  = (const float*)d_in[6];
    const float* gad  = (const float*)d_in[7];
    const float* gb   = (const float*)d_in[8];
    const float* s2Wl = (const float*)d_in[9];
    const float* s2Wr = (const float*)d_in[10];
    const float* s2b  = (const float*)d_in[11];
    const float* clsW = (const float*)d_in[12];
    const float* clsb = (const float*)d_in[13];
    float* out = (float*)d_out;
    const int* src = ei;            // edge_index[0]
    const int* dst = ei + N_EDGES;  // edge_index[1]

    // ---- workspace layout (all fully rewritten each call; no stale reads) ----
    float* ws  = (float*)d_ws;
    float* A   = ws;                                  // N*256 (h1, then h3)
    float* C   = A + (size_t)N_NODES * 256;           // N*128 (gat h; later sage2 mean)
    float* D   = C + (size_t)N_NODES * 128;           // N*128 (sage1 mean(20); later gat out/h2)
    float* as_ = D + (size_t)N_NODES * 128;           // N*4
    float* ad_ = as_ + N_NODES * 4;                   // N*4
    int* deg     = (int*)(ad_ + N_NODES * 4);         // N
    int* bsum    = deg + N_NODES;                     // NCHUNK
    int* rowptr  = bsum + 256;                        // N+1
    int* csr_src = rowptr + N_NODES + 1;              // E
    unsigned short* Wt1 = (unsigned short*)(csr_src + N_EDGES);  // 256*64
    unsigned short* Wt2 = Wt1 + 256 * 64;                        // 128*256
    unsigned short* Wt3 = Wt2 + 128 * 256;                       // 256*256

    const int MB = (N_NODES + 127) / 128;             // 391 row-blocks

    // ---- weight transpose + bf16 cast (tiny) ----
    wt_k<<<(256 * 64 + TPB - 1) / TPB, TPB, 0, stream>>>(s1Wl, 20, s1Wr, 20, 256, 64, Wt1);
    wt_k<<<(128 * 256 + TPB - 1) / TPB, TPB, 0, stream>>>(gW, 256, nullptr, 0, 128, 256, Wt2);
    wt_k<<<(256 * 256 + TPB - 1) / TPB, TPB, 0, stream>>>(s2Wl, 128, s2Wr, 128, 256, 256, Wt3);

    // ---- CSR build (hierarchical scan) ----
    hipMemsetAsync(deg, 0, N_NODES * sizeof(int), stream);
    hist_k<<<(N_EDGES + TPB - 1) / TPB, TPB, 0, stream>>>(dst, deg);
    scan1_k<<<NCHUNK, 256, 0, stream>>>(deg, rowptr, bsum);
    scan2_k<<<1, 256, 0, stream>>>(bsum);
    scan3_k<<<NCHUNK, 256, 0, stream>>>(rowptr, bsum);
    fill_k<<<(N_EDGES + TPB - 1) / TPB, TPB, 0, stream>>>(src, dst, rowptr, deg, csr_src);

    // ---- SAGE1:  A = relu([mean(x) | x] @ [Wl ; Wr] + b),  K=40 (Kp=64) ----
    gather_mean<20, 64><<<N_NODES, 64, 0, stream>>>(rowptr, csr_src, x, D);
    gemm_mfma<1><<<dim3(2, MB), 256, 0, stream>>>(D, 20, x, 20, Wt1, 64, s1b, A, 256);

    // ---- GAT:  C = A @ gW,  K=256 ----
    gemm_mfma<0><<<dim3(1, MB), 256, 0, stream>>>(A, 256, nullptr, 0, Wt2, 256,
                                                  nullptr, C, 128);
    att_scores<<<(N_NODES * 4 + TPB - 1) / TPB, TPB, 0, stream>>>(C, gas, gad, as_, ad_);
    gat_gather4<<<N_NODES / 8, 256, 0, stream>>>(rowptr, csr_src, (const float4*)C,
                                                 as_, ad_, gb, (float4*)D);

    // ---- SAGE2:  A = relu([mean(D) | D] @ [Wl ; Wr] + b),  K=256 ----
    gather_mean4<<<N_NODES / 8, 256, 0, stream>>>(rowptr, csr_src, (const float4*)D,
                                                  (float4*)C);
    gemm_mfma<1><<<dim3(2, MB), 256, 0, stream>>>(C, 128, D, 128, Wt3, 256, s2b, A, 256);

    // ---- classifier ----
    cls_k<<<(N_NODES + TPB - 1) / TPB, TPB, 0, stream>>>(A, clsW, clsb, out);
}

// Round 14
// 353.372 us; speedup vs baseline: 7.2467x; 1.0867x over previous
//
#include <hip/hip_runtime.h>
#include <math.h>

#define N_NODES 50000
#define N_EDGES 800000
#define TPB 256
#define NCHUNK ((N_NODES + 255) / 256)   // 196 scan blocks

typedef short s16x8 __attribute__((ext_vector_type(8)));
typedef float f32x4 __attribute__((ext_vector_type(4)));

__device__ __forceinline__ unsigned short f2bf(float f) {
    unsigned u = __float_as_uint(f);
    u += 0x7fffu + ((u >> 16) & 1u);          // round-to-nearest-even
    return (unsigned short)(u >> 16);
}
__device__ __forceinline__ float bf2f(unsigned short h) {
    return __uint_as_float(((unsigned)h) << 16);
}

// ---------------- weight pre-transpose + bf16 cast ----------------
__global__ void wt_k(const float* __restrict__ W1, int K1,
                     const float* __restrict__ W2, int K2,
                     int NO, int Kp, unsigned short* __restrict__ Wt) {
    int idx = blockIdx.x * TPB + threadIdx.x;
    if (idx >= NO * Kp) return;
    int n = idx / Kp, k = idx - n * Kp;
    float v = 0.f;
    if (k < K1) v = W1[(size_t)k * NO + n];
    else if (k < K1 + K2) v = W2[(size_t)(k - K1) * NO + n];
    Wt[idx] = f2bf(v);
}

// f32 [N][128] -> bf16 copy (for gather kernels; identical rounding to GEMM staging)
__global__ void cast_k(const float4* __restrict__ in4, ushort4* __restrict__ outb) {
    int idx = blockIdx.x * TPB + threadIdx.x;
    if (idx >= N_NODES * 32) return;
    float4 v = in4[idx];
    ushort4 b;
    b.x = f2bf(v.x); b.y = f2bf(v.y); b.z = f2bf(v.z); b.w = f2bf(v.w);
    outb[idx] = b;
}

// ---------------- bf16 MFMA GEMM, f32 A inputs (SAGE1 / GAT) ----------------
template<int ACT>
__global__ void gemm_mfma(const float* __restrict__ A1, int K1,
                          const float* __restrict__ A2, int K2,
                          const unsigned short* __restrict__ Wt, int Kp,
                          const float* __restrict__ bias,
                          float* __restrict__ out, int NO) {
    constexpr int BM = 128, BK = 32, LDP = 40;
    __shared__ unsigned short sA[BM * LDP];
    __shared__ unsigned short sB[128 * LDP];
    const int K = K1 + K2;
    const int T = Kp / BK;
    const int tid = threadIdx.x;
    const int lane = tid & 63, wid = tid >> 6;
    const int wr = wid >> 1, wc = wid & 1;
    const int row0 = blockIdx.y * BM, col0 = blockIdx.x * 128;
    const int l15 = lane & 15, l4 = lane >> 4;
    f32x4 acc[4][4] = {};

    for (int t = 0; t < T; ++t) {
        __syncthreads();
#pragma unroll
        for (int j = 0; j < 4; ++j) {
            int e = tid + j * 256;
            int r = e >> 3, k4 = e & 7;
            int kg = t * BK + k4 * 4, mg = row0 + r;
            float4 v = {0.f, 0.f, 0.f, 0.f};
            if (mg < N_NODES) {
                if (kg < K1)     v = *(const float4*)&A1[(size_t)mg * K1 + kg];
                else if (kg < K) v = *(const float4*)&A2[(size_t)mg * K2 + (kg - K1)];
            }
            ushort4 b;
            b.x = f2bf(v.x); b.y = f2bf(v.y); b.z = f2bf(v.z); b.w = f2bf(v.w);
            *(ushort4*)&sA[r * LDP + k4 * 4] = b;
        }
#pragma unroll
        for (int j = 0; j < 2; ++j) {
            int e = tid + j * 256;
            int n = e >> 2, k8 = e & 3;
            int4 v = *(const int4*)&Wt[(size_t)(col0 + n) * Kp + t * BK + k8 * 8];
            *(int4*)&sB[n * LDP + k8 * 8] = v;
        }
        __syncthreads();
        s16x8 af[4], bfr[4];
#pragma unroll
        for (int i = 0; i < 4; ++i) {
            af[i]  = *(const s16x8*)&sA[(wr * 64 + i * 16 + l15) * LDP + l4 * 8];
            bfr[i] = *(const s16x8*)&sB[(wc * 64 + i * 16 + l15) * LDP + l4 * 8];
        }
#pragma unroll
        for (int mi = 0; mi < 4; ++mi)
#pragma unroll
            for (int ni = 0; ni < 4; ++ni)
                acc[mi][ni] = __builtin_amdgcn_mfma_f32_16x16x32_bf16(
                    af[mi], bfr[ni], acc[mi][ni], 0, 0, 0);
    }
#pragma unroll
    for (int mi = 0; mi < 4; ++mi) {
#pragma unroll
        for (int ni = 0; ni < 4; ++ni) {
            int col = col0 + wc * 64 + ni * 16 + l15;
            float bb = bias ? bias[col] : 0.f;
#pragma unroll
            for (int r = 0; r < 4; ++r) {
                int row = row0 + wr * 64 + mi * 16 + l4 * 4 + r;
                if (row < N_NODES) {
                    float v = acc[mi][ni][r] + bb;
                    if (ACT) v = fmaxf(v, 0.f);
                    out[(size_t)row * NO + col] = v;
                }
            }
        }
    }
}

// ---------------- bf16 MFMA GEMM, bf16 A inputs (SAGE2) ----------------
// A1,A2 bf16 [M][K1],[M][K2]; K1,K2 multiples of 32 (tiles never straddle).
template<int ACT>
__global__ void gemm_mfma_bf(const unsigned short* __restrict__ A1, int K1,
                             const unsigned short* __restrict__ A2, int K2,
                             const unsigned short* __restrict__ Wt, int Kp,
                             const float* __restrict__ bias,
                             float* __restrict__ out, int NO) {
    constexpr int BM = 128, BK = 32, LDP = 40;
    __shared__ unsigned short sA[BM * LDP];
    __shared__ unsigned short sB[128 * LDP];
    const int T = Kp / BK;
    const int tid = threadIdx.x;
    const int lane = tid & 63, wid = tid >> 6;
    const int wr = wid >> 1, wc = wid & 1;
    const int row0 = blockIdx.y * BM, col0 = blockIdx.x * 128;
    const int l15 = lane & 15, l4 = lane >> 4;
    f32x4 acc[4][4] = {};

    for (int t = 0; t < T; ++t) {
        __syncthreads();
        // stage A: 128 rows x 32 k bf16 = 512 int4 chunks (16B copies)
#pragma unroll
        for (int j = 0; j < 2; ++j) {
            int e = tid + j * 256;
            int r = e >> 2, k8 = e & 3;
            int kg = t * BK + k8 * 8, mg = row0 + r;
            int4 v = {0, 0, 0, 0};
            if (mg < N_NODES) {
                if (kg < K1) v = *(const int4*)&A1[(size_t)mg * K1 + kg];
                else         v = *(const int4*)&A2[(size_t)mg * K2 + (kg - K1)];
            }
            *(int4*)&sA[r * LDP + k8 * 8] = v;
        }
#pragma unroll
        for (int j = 0; j < 2; ++j) {
            int e = tid + j * 256;
            int n = e >> 2, k8 = e & 3;
            int4 v = *(const int4*)&Wt[(size_t)(col0 + n) * Kp + t * BK + k8 * 8];
            *(int4*)&sB[n * LDP + k8 * 8] = v;
        }
        __syncthreads();
        s16x8 af[4], bfr[4];
#pragma unroll
        for (int i = 0; i < 4; ++i) {
            af[i]  = *(const s16x8*)&sA[(wr * 64 + i * 16 + l15) * LDP + l4 * 8];
            bfr[i] = *(const s16x8*)&sB[(wc * 64 + i * 16 + l15) * LDP + l4 * 8];
        }
#pragma unroll
        for (int mi = 0; mi < 4; ++mi)
#pragma unroll
            for (int ni = 0; ni < 4; ++ni)
                acc[mi][ni] = __builtin_amdgcn_mfma_f32_16x16x32_bf16(
                    af[mi], bfr[ni], acc[mi][ni], 0, 0, 0);
    }
#pragma unroll
    for (int mi = 0; mi < 4; ++mi) {
#pragma unroll
        for (int ni = 0; ni < 4; ++ni) {
            int col = col0 + wc * 64 + ni * 16 + l15;
            float bb = bias ? bias[col] : 0.f;
#pragma unroll
            for (int r = 0; r < 4; ++r) {
                int row = row0 + wr * 64 + mi * 16 + l4 * 4 + r;
                if (row < N_NODES) {
                    float v = acc[mi][ni][r] + bb;
                    if (ACT) v = fmaxf(v, 0.f);
                    out[(size_t)row * NO + col] = v;
                }
            }
        }
    }
}

// ---------------- CSR construction ----------------
__global__ void hist_k(const int* __restrict__ dst, int* __restrict__ deg) {
    int e = blockIdx.x * TPB + threadIdx.x;
    if (e < N_EDGES) atomicAdd(&deg[dst[e]], 1);
}

__global__ void scan1_k(const int* __restrict__ deg, int* __restrict__ rowptr,
                        int* __restrict__ bsum) {
    __shared__ int tmp[256];
    int tid = threadIdx.x;
    int idx = blockIdx.x * 256 + tid;
    int v = (idx < N_NODES) ? deg[idx] : 0;
    tmp[tid] = v;
    __syncthreads();
    for (int off = 1; off < 256; off <<= 1) {
        int t = (tid >= off) ? tmp[tid - off] : 0;
        __syncthreads();
        tmp[tid] += t;
        __syncthreads();
    }
    if (idx < N_NODES) rowptr[idx] = tmp[tid] - v;
    if (tid == 255) bsum[blockIdx.x] = tmp[255];
}

__global__ void scan2_k(int* __restrict__ bsum) {
    __shared__ int tmp[256];
    int tid = threadIdx.x;
    int v = (tid < NCHUNK) ? bsum[tid] : 0;
    tmp[tid] = v;
    __syncthreads();
    for (int off = 1; off < 256; off <<= 1) {
        int t = (tid >= off) ? tmp[tid - off] : 0;
        __syncthreads();
        tmp[tid] += t;
        __syncthreads();
    }
    if (tid < NCHUNK) bsum[tid] = tmp[tid] - v;
}

__global__ void scan3_k(int* __restrict__ rowptr, const int* __restrict__ bsum) {
    int idx = blockIdx.x * 256 + threadIdx.x;
    if (idx < N_NODES) rowptr[idx] += bsum[blockIdx.x];
    if (idx == 0) rowptr[N_NODES] = N_EDGES;
}

__global__ void fill_k(const int* __restrict__ src, const int* __restrict__ dst,
                       const int* __restrict__ rowptr, int* __restrict__ deg,
                       int* __restrict__ csr_src) {
    int e = blockIdx.x * TPB + threadIdx.x;
    if (e >= N_EDGES) return;
    int d = dst[e];
    int r = atomicSub(&deg[d], 1) - 1;
    csr_src[rowptr[d] + r] = src[e];
}

// ---------------- gather aggregations ----------------
template<int F, int BLK>
__global__ void gather_mean(const int* __restrict__ rowptr, const int* __restrict__ csr_src,
                            const float* __restrict__ feat, float* __restrict__ out) {
    int n = blockIdx.x;
    int c = threadIdx.x;
    if (c >= F) return;
    int e0 = rowptr[n], e1 = rowptr[n + 1];
    float acc = 0.f;
    for (int e = e0; e < e1; ++e)
        acc += feat[(size_t)csr_src[e] * F + c];
    out[(size_t)n * F + c] = acc / fmaxf((float)(e1 - e0), 1.0f);
}

// bf16-in, bf16-out mean for F=128: 32 lanes/node, 8 nodes per block, 2-unrolled
__global__ void gather_mean_bf(const int* __restrict__ rowptr, const int* __restrict__ csr_src,
                               const unsigned short* __restrict__ featb,
                               unsigned short* __restrict__ outb) {
    int tid = threadIdx.x;
    int n = blockIdx.x * 8 + (tid >> 5);
    int c = tid & 31;
    int e0 = rowptr[n], e1 = rowptr[n + 1];
    float4 acc = {0.f, 0.f, 0.f, 0.f};
    int e = e0;
    for (; e + 1 < e1; e += 2) {
        int s0 = csr_src[e], s1 = csr_src[e + 1];
        ushort4 u0 = *(const ushort4*)&featb[(size_t)s0 * 128 + c * 4];
        ushort4 u1 = *(const ushort4*)&featb[(size_t)s1 * 128 + c * 4];
        acc.x += bf2f(u0.x) + bf2f(u1.x); acc.y += bf2f(u0.y) + bf2f(u1.y);
        acc.z += bf2f(u0.z) + bf2f(u1.z); acc.w += bf2f(u0.w) + bf2f(u1.w);
    }
    if (e < e1) {
        ushort4 u = *(const ushort4*)&featb[(size_t)csr_src[e] * 128 + c * 4];
        acc.x += bf2f(u.x); acc.y += bf2f(u.y); acc.z += bf2f(u.z); acc.w += bf2f(u.w);
    }
    float inv = 1.0f / fmaxf((float)(e1 - e0), 1.0f);
    ushort4 o;
    o.x = f2bf(acc.x * inv); o.y = f2bf(acc.y * inv);
    o.z = f2bf(acc.z * inv); o.w = f2bf(acc.w * inv);
    *(ushort4*)&outb[(size_t)n * 128 + c * 4] = o;
}

// per-(node,head) attention scores (reads f32 h)
__global__ void att_scores(const float* __restrict__ h, const float* __restrict__ att_src,
                           const float* __restrict__ att_dst, float* __restrict__ as_,
                           float* __restrict__ ad_) {
    int idx = blockIdx.x * TPB + threadIdx.x;
    if (idx >= N_NODES * 4) return;
    int n = idx >> 2, hd = idx & 3;
    const float* row = h + (size_t)n * 128 + hd * 32;
    float sa = 0.f, sd = 0.f;
    for (int c = 0; c < 32; ++c) {
        float v = row[c];
        sa = fmaf(v, att_src[hd * 32 + c], sa);
        sd = fmaf(v, att_dst[hd * 32 + c], sd);
    }
    as_[idx] = sa;
    ad_[idx] = sd;
}

// fused GAT aggregation: bf16 h gather, 2-edge-unrolled online softmax, ELU, bf16 out
__global__ void gat_gather_bf(const int* __restrict__ rowptr, const int* __restrict__ csr_src,
                              const unsigned short* __restrict__ hb,
                              const float* __restrict__ as_, const float* __restrict__ ad_,
                              const float* __restrict__ gb,
                              unsigned short* __restrict__ outb) {
    int tid = threadIdx.x;
    int n = blockIdx.x * 8 + (tid >> 5);
    int c = tid & 31;              // float4 index within row; head = c>>3
    int hd = c >> 3;
    int e0 = rowptr[n], e1 = rowptr[n + 1];
    float ad = ad_[n * 4 + hd];
    float m = -INFINITY, s = 0.f;
    float4 acc = {0.f, 0.f, 0.f, 0.f};
    int e = e0;
    for (; e + 1 < e1; e += 2) {
        int s0 = csr_src[e], s1 = csr_src[e + 1];
        float a0 = as_[s0 * 4 + hd] + ad;
        float a1 = as_[s1 * 4 + hd] + ad;
        a0 = a0 >= 0.f ? a0 : 0.2f * a0;
        a1 = a1 >= 0.f ? a1 : 0.2f * a1;
        float pm = fmaxf(a0, a1);
        if (pm > m) {                              // one rescale per 2 edges
            float sc = __expf(m - pm);
            s *= sc; acc.x *= sc; acc.y *= sc; acc.z *= sc; acc.w *= sc;
            m = pm;
        }
        float ex0 = __expf(a0 - m), ex1 = __expf(a1 - m);
        s += ex0 + ex1;
        ushort4 u0 = *(const ushort4*)&hb[(size_t)s0 * 128 + c * 4];
        ushort4 u1 = *(const ushort4*)&hb[(size_t)s1 * 128 + c * 4];
        acc.x = fmaf(bf2f(u0.x), ex0, acc.x); acc.y = fmaf(bf2f(u0.y), ex0, acc.y);
        acc.z = fmaf(bf2f(u0.z), ex0, acc.z); acc.w = fmaf(bf2f(u0.w), ex0, acc.w);
        acc.x = fmaf(bf2f(u1.x), ex1, acc.x); acc.y = fmaf(bf2f(u1.y), ex1, acc.y);
        acc.z = fmaf(bf2f(u1.z), ex1, acc.z); acc.w = fmaf(bf2f(u1.w), ex1, acc.w);
    }
    if (e < e1) {
        int s0 = csr_src[e];
        float a = as_[s0 * 4 + hd] + ad;
        a = a >= 0.f ? a : 0.2f * a;
        if (a > m) {
            float sc = __expf(m - a);
            s *= sc; acc.x *= sc; acc.y *= sc; acc.z *= sc; acc.w *= sc;
            m = a;
        }
        float ex = __expf(a - m);
        s += ex;
        ushort4 u = *(const ushort4*)&hb[(size_t)s0 * 128 + c * 4];
        acc.x = fmaf(bf2f(u.x), ex, acc.x); acc.y = fmaf(bf2f(u.y), ex, acc.y);
        acc.z = fmaf(bf2f(u.z), ex, acc.z); acc.w = fmaf(bf2f(u.w), ex, acc.w);
    }
    float inv = 1.0f / (s + 1e-16f);
    float rx = acc.x * inv + gb[c * 4 + 0];
    float ry = acc.y * inv + gb[c * 4 + 1];
    float rz = acc.z * inv + gb[c * 4 + 2];
    float rw = acc.w * inv + gb[c * 4 + 3];
    rx = rx > 0.f ? rx : expm1f(rx);
    ry = ry > 0.f ? ry : expm1f(ry);
    rz = rz > 0.f ? rz : expm1f(rz);
    rw = rw > 0.f ? rw : expm1f(rw);
    ushort4 o;
    o.x = f2bf(rx); o.y = f2bf(ry); o.z = f2bf(rz); o.w = f2bf(rw);
    *(ushort4*)&outb[(size_t)n * 128 + c * 4] = o;
}

// classifier: [N,256] @ [256,5] + b   (f32)
__global__ void cls_k(const float* __restrict__ h, const float* __restrict__ W,
                      const float* __restrict__ b, float* __restrict__ out) {
    __shared__ float sW[256 * 5];
    for (int i = threadIdx.x; i < 1280; i += TPB) sW[i] = W[i];
    __syncthreads();
    int n = blockIdx.x * TPB + threadIdx.x;
    if (n >= N_NODES) return;
    const float4* row = (const float4*)(h + (size_t)n * 256);
    float acc[5] = {0.f, 0.f, 0.f, 0.f, 0.f};
    for (int k4 = 0; k4 < 64; ++k4) {
        float4 v = row[k4];
        const float* w = &sW[k4 * 4 * 5];
#pragma unroll
        for (int c = 0; c < 5; ++c) acc[c] = fmaf(v.x, w[c], acc[c]);
#pragma unroll
        for (int c = 0; c < 5; ++c) acc[c] = fmaf(v.y, w[5 + c], acc[c]);
#pragma unroll
        for (int c = 0; c < 5; ++c) acc[c] = fmaf(v.z, w[10 + c], acc[c]);
#pragma unroll
        for (int c = 0; c < 5; ++c) acc[c] = fmaf(v.w, w[15 + c], acc[c]);
    }
#pragma unroll
    for (int c = 0; c < 5; ++c) out[(size_t)n * 5 + c] = acc[c] + b[c];
}

extern "C" void kernel_launch(void* const* d_in, const int* in_sizes, int n_in,
                              void* d_out, int out_size, void* d_ws, size_t ws_size,
                              hipStream_t stream) {
    const float* x    = (const float*)d_in[0];
    const int*   ei   = (const int*)d_in[1];
    const float* s1Wl = (const float*)d_in[2];
    const float* s1Wr = (const float*)d_in[3];
    const float* s1b  = (const float*)d_in[4];
    const float* gW   = (const float*)d_in[5];
    const float* gas  = (const float*)d_in[6];
    const float* gad  = (const float*)d_in[7];
    const float* gb   = (const float*)d_in[8];
    const float* s2Wl = (const float*)d_in[9];
    const float* s2Wr = (const float*)d_in[10];
    const float* s2b  = (const float*)d_in[11];
    const float* clsW = (const float*)d_in[12];
    const float* clsb = (const float*)d_in[13];
    float* out = (float*)d_out;
    const int* src = ei;            // edge_index[0]
    const int* dst = ei + N_EDGES;  // edge_index[1]

    // ---- workspace layout ----
    float* ws  = (float*)d_ws;
    float* A   = ws;                                  // N*256 f32 (h1, then h3)
    float* C   = A + (size_t)N_NODES * 256;           // N*128 f32 (sage1 mean20, then gat h)
    float* as_ = C + (size_t)N_NODES * 128;           // N*4
    float* ad_ = as_ + N_NODES * 4;                   // N*4
    int* deg     = (int*)(ad_ + N_NODES * 4);         // N
    int* bsum    = deg + N_NODES;                     // 256
    int* rowptr  = bsum + 256;                        // N+1
    int* csr_src = rowptr + N_NODES + 1;              // E
    unsigned short* Wt1 = (unsigned short*)(csr_src + N_EDGES);  // 256*64
    unsigned short* Wt2 = Wt1 + 256 * 64;                        // 128*256
    unsigned short* Wt3 = Wt2 + 128 * 256;                       // 256*256
    unsigned short* Cb  = Wt3 + 256 * 256;                       // N*128 bf16 (gat h)
    unsigned short* Db  = Cb + (size_t)N_NODES * 128;            // N*128 bf16 (gat out)
    unsigned short* Mb  = Db + (size_t)N_NODES * 128;            // N*128 bf16 (sage2 mean)

    const int MB = (N_NODES + 127) / 128;             // 391 row-blocks

    // ---- weight transpose + bf16 cast (tiny) ----
    wt_k<<<(256 * 64 + TPB - 1) / TPB, TPB, 0, stream>>>(s1Wl, 20, s1Wr, 20, 256, 64, Wt1);
    wt_k<<<(128 * 256 + TPB - 1) / TPB, TPB, 0, stream>>>(gW, 256, nullptr, 0, 128, 256, Wt2);
    wt_k<<<(256 * 256 + TPB - 1) / TPB, TPB, 0, stream>>>(s2Wl, 128, s2Wr, 128, 256, 256, Wt3);

    // ---- CSR build (hierarchical scan) ----
    hipMemsetAsync(deg, 0, N_NODES * sizeof(int), stream);
    hist_k<<<(N_EDGES + TPB - 1) / TPB, TPB, 0, stream>>>(dst, deg);
    scan1_k<<<NCHUNK, 256, 0, stream>>>(deg, rowptr, bsum);
    scan2_k<<<1, 256, 0, stream>>>(bsum);
    scan3_k<<<NCHUNK, 256, 0, stream>>>(rowptr, bsum);
    fill_k<<<(N_EDGES + TPB - 1) / TPB, TPB, 0, stream>>>(src, dst, rowptr, deg, csr_src);

    // ---- SAGE1:  A = relu([mean(x) | x] @ [Wl ; Wr] + b),  K=40 (Kp=64) ----
    gather_mean<20, 64><<<N_NODES, 64, 0, stream>>>(rowptr, csr_src, x, C);
    gemm_mfma<1><<<dim3(2, MB), 256, 0, stream>>>(C, 20, x, 20, Wt1, 64, s1b, A, 256);

    // ---- GAT:  C = A @ gW (f32), Cb = bf16(C);  scores; fused gather -> Db ----
    gemm_mfma<0><<<dim3(1, MB), 256, 0, stream>>>(A, 256, nullptr, 0, Wt2, 256,
                                                  nullptr, C, 128);
    att_scores<<<(N_NODES * 4 + TPB - 1) / TPB, TPB, 0, stream>>>(C, gas, gad, as_, ad_);
    cast_k<<<(N_NODES * 32 + TPB - 1) / TPB, TPB, 0, stream>>>((const float4*)C,
                                                               (ushort4*)Cb);
    gat_gather_bf<<<N_NODES / 8, 256, 0, stream>>>(rowptr, csr_src, Cb, as_, ad_, gb, Db);

    // ---- SAGE2:  A = relu([mean(Db) | Db] @ [Wl ; Wr] + b),  K=256, bf16 A ----
    gather_mean_bf<<<N_NODES / 8, 256, 0, stream>>>(rowptr, csr_src, Db, Mb);
    gemm_mfma_bf<1><<<dim3(2, MB), 256, 0, stream>>>(Mb, 128, Db, 128, Wt3, 256, s2b, A, 256);

    // ---- classifier ----
    cls_k<<<(N_NODES + TPB - 1) / TPB, TPB, 0, stream>>>(A, clsW, clsb, out);
}

// Round 15
// 296.026 us; speedup vs baseline: 8.6505x; 1.1937x over previous
//
#include <hip/hip_runtime.h>
#include <math.h>

#define N_NODES 50000
#define N_EDGES 800000
#define TPB 256
#define NCHUNK ((N_NODES + 255) / 256)   // 196 scan blocks

typedef short s16x8 __attribute__((ext_vector_type(8)));
typedef float f32x4 __attribute__((ext_vector_type(4)));

__device__ __forceinline__ unsigned short f2bf(float f) {
    unsigned u = __float_as_uint(f);
    u += 0x7fffu + ((u >> 16) & 1u);          // round-to-nearest-even
    return (unsigned short)(u >> 16);
}
__device__ __forceinline__ float bf2f(unsigned short h) {
    return __uint_as_float(((unsigned)h) << 16);
}

// ---------------- all weight transposes + bf16 cast, one launch ----------------
// Wt1: [256][64]  <- [s1Wl;s1Wr] (K=40, pad 64)
// Wt2: [128][256] <- gW (K=256)
// Wt3: [256][256] <- [s2Wl;s2Wr] (K=256)
__global__ void wt_all_k(const float* __restrict__ s1Wl, const float* __restrict__ s1Wr,
                         const float* __restrict__ gW, const float* __restrict__ s2Wl,
                         const float* __restrict__ s2Wr, unsigned short* __restrict__ Wt1,
                         unsigned short* __restrict__ Wt2, unsigned short* __restrict__ Wt3) {
    int idx = blockIdx.x * TPB + threadIdx.x;
    if (idx < 16384) {                       // 256*64
        int n = idx >> 6, k = idx & 63;
        float v = 0.f;
        if (k < 20) v = s1Wl[k * 256 + n];
        else if (k < 40) v = s1Wr[(k - 20) * 256 + n];
        Wt1[idx] = f2bf(v);
    } else if (idx < 49152) {                // + 128*256
        int j = idx - 16384;
        int n = j >> 8, k = j & 255;
        Wt2[j] = f2bf(gW[(size_t)k * 128 + n]);
    } else if (idx < 114688) {               // + 256*256
        int j = idx - 49152;
        int n = j >> 8, k = j & 255;
        float v = (k < 128) ? s2Wl[(size_t)k * 256 + n] : s2Wr[(size_t)(k - 128) * 256 + n];
        Wt3[j] = f2bf(v);
    }
}

// ---------------- bf16 MFMA GEMM, f32 A inputs (SAGE1) ----------------
// OBF: write bf16 output (relu folded) instead of f32.
template<int ACT, int OBF>
__global__ void gemm_mfma(const float* __restrict__ A1, int K1,
                          const float* __restrict__ A2, int K2,
                          const unsigned short* __restrict__ Wt, int Kp,
                          const float* __restrict__ bias,
                          float* __restrict__ out, unsigned short* __restrict__ outb,
                          int NO) {
    constexpr int BM = 128, BK = 32, LDP = 40;
    __shared__ unsigned short sA[BM * LDP];
    __shared__ unsigned short sB[128 * LDP];
    const int K = K1 + K2;
    const int T = Kp / BK;
    const int tid = threadIdx.x;
    const int lane = tid & 63, wid = tid >> 6;
    const int wr = wid >> 1, wc = wid & 1;
    const int row0 = blockIdx.y * BM, col0 = blockIdx.x * 128;
    const int l15 = lane & 15, l4 = lane >> 4;
    f32x4 acc[4][4] = {};

    for (int t = 0; t < T; ++t) {
        __syncthreads();
#pragma unroll
        for (int j = 0; j < 4; ++j) {
            int e = tid + j * 256;
            int r = e >> 3, k4 = e & 7;
            int kg = t * BK + k4 * 4, mg = row0 + r;
            float4 v = {0.f, 0.f, 0.f, 0.f};
            if (mg < N_NODES) {
                if (kg < K1)     v = *(const float4*)&A1[(size_t)mg * K1 + kg];
                else if (kg < K) v = *(const float4*)&A2[(size_t)mg * K2 + (kg - K1)];
            }
            ushort4 b;
            b.x = f2bf(v.x); b.y = f2bf(v.y); b.z = f2bf(v.z); b.w = f2bf(v.w);
            *(ushort4*)&sA[r * LDP + k4 * 4] = b;
        }
#pragma unroll
        for (int j = 0; j < 2; ++j) {
            int e = tid + j * 256;
            int n = e >> 2, k8 = e & 3;
            int4 v = *(const int4*)&Wt[(size_t)(col0 + n) * Kp + t * BK + k8 * 8];
            *(int4*)&sB[n * LDP + k8 * 8] = v;
        }
        __syncthreads();
        s16x8 af[4], bfr[4];
#pragma unroll
        for (int i = 0; i < 4; ++i) {
            af[i]  = *(const s16x8*)&sA[(wr * 64 + i * 16 + l15) * LDP + l4 * 8];
            bfr[i] = *(const s16x8*)&sB[(wc * 64 + i * 16 + l15) * LDP + l4 * 8];
        }
#pragma unroll
        for (int mi = 0; mi < 4; ++mi)
#pragma unroll
            for (int ni = 0; ni < 4; ++ni)
                acc[mi][ni] = __builtin_amdgcn_mfma_f32_16x16x32_bf16(
                    af[mi], bfr[ni], acc[mi][ni], 0, 0, 0);
    }
#pragma unroll
    for (int mi = 0; mi < 4; ++mi) {
#pragma unroll
        for (int ni = 0; ni < 4; ++ni) {
            int col = col0 + wc * 64 + ni * 16 + l15;
            float bb = bias ? bias[col] : 0.f;
#pragma unroll
            for (int r = 0; r < 4; ++r) {
                int row = row0 + wr * 64 + mi * 16 + l4 * 4 + r;
                if (row < N_NODES) {
                    float v = acc[mi][ni][r] + bb;
                    if (ACT) v = fmaxf(v, 0.f);
                    if (OBF) outb[(size_t)row * NO + col] = f2bf(v);
                    else     out[(size_t)row * NO + col] = v;
                }
            }
        }
    }
}

// ---------------- bf16 MFMA GEMM, bf16 A inputs (GAT / SAGE2) ----------------
// A1,A2 bf16; K1 (and K2) multiples of 8; BK tiles never straddle the seam
// (K1 % 32 == 0 when A2 != null).
template<int ACT, int OBF>
__global__ void gemm_mfma_bf(const unsigned short* __restrict__ A1, int K1,
                             const unsigned short* __restrict__ A2, int K2,
                             const unsigned short* __restrict__ Wt, int Kp,
                             const float* __restrict__ bias,
                             float* __restrict__ out, unsigned short* __restrict__ outb,
                             int NO) {
    constexpr int BM = 128, BK = 32, LDP = 40;
    __shared__ unsigned short sA[BM * LDP];
    __shared__ unsigned short sB[128 * LDP];
    const int T = Kp / BK;
    const int tid = threadIdx.x;
    const int lane = tid & 63, wid = tid >> 6;
    const int wr = wid >> 1, wc = wid & 1;
    const int row0 = blockIdx.y * BM, col0 = blockIdx.x * 128;
    const int l15 = lane & 15, l4 = lane >> 4;
    f32x4 acc[4][4] = {};

    for (int t = 0; t < T; ++t) {
        __syncthreads();
#pragma unroll
        for (int j = 0; j < 2; ++j) {
            int e = tid + j * 256;
            int r = e >> 2, k8 = e & 3;
            int kg = t * BK + k8 * 8, mg = row0 + r;
            int4 v = {0, 0, 0, 0};
            if (mg < N_NODES) {
                if (kg < K1) v = *(const int4*)&A1[(size_t)mg * K1 + kg];
                else         v = *(const int4*)&A2[(size_t)mg * K2 + (kg - K1)];
            }
            *(int4*)&sA[r * LDP + k8 * 8] = v;
        }
#pragma unroll
        for (int j = 0; j < 2; ++j) {
            int e = tid + j * 256;
            int n = e >> 2, k8 = e & 3;
            int4 v = *(const int4*)&Wt[(size_t)(col0 + n) * Kp + t * BK + k8 * 8];
            *(int4*)&sB[n * LDP + k8 * 8] = v;
        }
        __syncthreads();
        s16x8 af[4], bfr[4];
#pragma unroll
        for (int i = 0; i < 4; ++i) {
            af[i]  = *(const s16x8*)&sA[(wr * 64 + i * 16 + l15) * LDP + l4 * 8];
            bfr[i] = *(const s16x8*)&sB[(wc * 64 + i * 16 + l15) * LDP + l4 * 8];
        }
#pragma unroll
        for (int mi = 0; mi < 4; ++mi)
#pragma unroll
            for (int ni = 0; ni < 4; ++ni)
                acc[mi][ni] = __builtin_amdgcn_mfma_f32_16x16x32_bf16(
                    af[mi], bfr[ni], acc[mi][ni], 0, 0, 0);
    }
#pragma unroll
    for (int mi = 0; mi < 4; ++mi) {
#pragma unroll
        for (int ni = 0; ni < 4; ++ni) {
            int col = col0 + wc * 64 + ni * 16 + l15;
            float bb = bias ? bias[col] : 0.f;
#pragma unroll
            for (int r = 0; r < 4; ++r) {
                int row = row0 + wr * 64 + mi * 16 + l4 * 4 + r;
                if (row < N_NODES) {
                    float v = acc[mi][ni][r] + bb;
                    if (ACT) v = fmaxf(v, 0.f);
                    if (OBF) outb[(size_t)row * NO + col] = f2bf(v);
                    else     out[(size_t)row * NO + col] = v;
                }
            }
        }
    }
}

// ---------------- CSR construction ----------------
__global__ void hist_k(const int* __restrict__ dst, int* __restrict__ deg) {
    int e = blockIdx.x * TPB + threadIdx.x;
    if (e < N_EDGES) atomicAdd(&deg[dst[e]], 1);
}

__global__ void scan1_k(const int* __restrict__ deg, int* __restrict__ rowptr,
                        int* __restrict__ bsum) {
    __shared__ int tmp[256];
    int tid = threadIdx.x;
    int idx = blockIdx.x * 256 + tid;
    int v = (idx < N_NODES) ? deg[idx] : 0;
    tmp[tid] = v;
    __syncthreads();
    for (int off = 1; off < 256; off <<= 1) {
        int t = (tid >= off) ? tmp[tid - off] : 0;
        __syncthreads();
        tmp[tid] += t;
        __syncthreads();
    }
    if (idx < N_NODES) rowptr[idx] = tmp[tid] - v;
    if (tid == 255) bsum[blockIdx.x] = tmp[255];
}

__global__ void scan2_k(int* __restrict__ bsum) {
    __shared__ int tmp[256];
    int tid = threadIdx.x;
    int v = (tid < NCHUNK) ? bsum[tid] : 0;
    tmp[tid] = v;
    __syncthreads();
    for (int off = 1; off < 256; off <<= 1) {
        int t = (tid >= off) ? tmp[tid - off] : 0;
        __syncthreads();
        tmp[tid] += t;
        __syncthreads();
    }
    if (tid < NCHUNK) bsum[tid] = tmp[tid] - v;
}

__global__ void scan3_k(int* __restrict__ rowptr, const int* __restrict__ bsum) {
    int idx = blockIdx.x * 256 + threadIdx.x;
    if (idx < N_NODES) rowptr[idx] += bsum[blockIdx.x];
    if (idx == 0) rowptr[N_NODES] = N_EDGES;
}

__global__ void fill_k(const int* __restrict__ src, const int* __restrict__ dst,
                       const int* __restrict__ rowptr, int* __restrict__ deg,
                       int* __restrict__ csr_src) {
    int e = blockIdx.x * TPB + threadIdx.x;
    if (e >= N_EDGES) return;
    int d = dst[e];
    int r = atomicSub(&deg[d], 1) - 1;
    csr_src[rowptr[d] + r] = src[e];
}

// ---------------- gather aggregations ----------------
// SAGE1 mean (F=20, f32): 32-lane group per node, 8 nodes per 256-block
__global__ void gm20_k(const int* __restrict__ rowptr, const int* __restrict__ csr_src,
                       const float* __restrict__ feat, float* __restrict__ out) {
    int tid = threadIdx.x;
    int n = blockIdx.x * 8 + (tid >> 5);
    int c = tid & 31;
    if (n >= N_NODES || c >= 20) return;
    int e0 = rowptr[n], e1 = rowptr[n + 1];
    float acc = 0.f;
    int e = e0;
    for (; e + 1 < e1; e += 2) {
        acc += feat[(size_t)csr_src[e] * 20 + c] + feat[(size_t)csr_src[e + 1] * 20 + c];
    }
    if (e < e1) acc += feat[(size_t)csr_src[e] * 20 + c];
    out[(size_t)n * 20 + c] = acc / fmaxf((float)(e1 - e0), 1.0f);
}

// bf16 mean for F=128: 32 lanes/node, 8 nodes/block, 4-edge unroll
__global__ void gather_mean_bf(const int* __restrict__ rowptr, const int* __restrict__ csr_src,
                               const unsigned short* __restrict__ featb,
                               unsigned short* __restrict__ outb) {
    int tid = threadIdx.x;
    int n = blockIdx.x * 8 + (tid >> 5);
    int c = tid & 31;
    int e0 = rowptr[n], e1 = rowptr[n + 1];
    float4 acc = {0.f, 0.f, 0.f, 0.f};
    int e = e0;
    for (; e + 3 < e1; e += 4) {
        int s0 = csr_src[e], s1 = csr_src[e + 1], s2 = csr_src[e + 2], s3 = csr_src[e + 3];
        ushort4 u0 = *(const ushort4*)&featb[(size_t)s0 * 128 + c * 4];
        ushort4 u1 = *(const ushort4*)&featb[(size_t)s1 * 128 + c * 4];
        ushort4 u2 = *(const ushort4*)&featb[(size_t)s2 * 128 + c * 4];
        ushort4 u3 = *(const ushort4*)&featb[(size_t)s3 * 128 + c * 4];
        acc.x += (bf2f(u0.x) + bf2f(u1.x)) + (bf2f(u2.x) + bf2f(u3.x));
        acc.y += (bf2f(u0.y) + bf2f(u1.y)) + (bf2f(u2.y) + bf2f(u3.y));
        acc.z += (bf2f(u0.z) + bf2f(u1.z)) + (bf2f(u2.z) + bf2f(u3.z));
        acc.w += (bf2f(u0.w) + bf2f(u1.w)) + (bf2f(u2.w) + bf2f(u3.w));
    }
    for (; e < e1; ++e) {
        ushort4 u = *(const ushort4*)&featb[(size_t)csr_src[e] * 128 + c * 4];
        acc.x += bf2f(u.x); acc.y += bf2f(u.y); acc.z += bf2f(u.z); acc.w += bf2f(u.w);
    }
    float inv = 1.0f / fmaxf((float)(e1 - e0), 1.0f);
    ushort4 o;
    o.x = f2bf(acc.x * inv); o.y = f2bf(acc.y * inv);
    o.z = f2bf(acc.z * inv); o.w = f2bf(acc.w * inv);
    *(ushort4*)&outb[(size_t)n * 128 + c * 4] = o;
}

// per-(node,head) attention scores, bf16 h
__global__ void att_scores_bf(const unsigned short* __restrict__ hb,
                              const float* __restrict__ att_src,
                              const float* __restrict__ att_dst,
                              float* __restrict__ as_, float* __restrict__ ad_) {
    int idx = blockIdx.x * TPB + threadIdx.x;
    if (idx >= N_NODES * 4) return;
    int n = idx >> 2, hd = idx & 3;
    const unsigned short* row = hb + (size_t)n * 128 + hd * 32;
    float sa = 0.f, sd = 0.f;
#pragma unroll
    for (int c4 = 0; c4 < 8; ++c4) {
        ushort4 u = *(const ushort4*)&row[c4 * 4];
        const float* asr = &att_src[hd * 32 + c4 * 4];
        const float* adr = &att_dst[hd * 32 + c4 * 4];
        sa = fmaf(bf2f(u.x), asr[0], sa); sd = fmaf(bf2f(u.x), adr[0], sd);
        sa = fmaf(bf2f(u.y), asr[1], sa); sd = fmaf(bf2f(u.y), adr[1], sd);
        sa = fmaf(bf2f(u.z), asr[2], sa); sd = fmaf(bf2f(u.z), adr[2], sd);
        sa = fmaf(bf2f(u.w), asr[3], sa); sd = fmaf(bf2f(u.w), adr[3], sd);
    }
    as_[idx] = sa;
    ad_[idx] = sd;
}

// fused GAT aggregation: bf16 gather, 4-edge-unrolled online softmax, ELU, bf16 out
__global__ void gat_gather_bf(const int* __restrict__ rowptr, const int* __restrict__ csr_src,
                              const unsigned short* __restrict__ hb,
                              const float* __restrict__ as_, const float* __restrict__ ad_,
                              const float* __restrict__ gb,
                              unsigned short* __restrict__ outb) {
    int tid = threadIdx.x;
    int n = blockIdx.x * 8 + (tid >> 5);
    int c = tid & 31;              // float4 index within row; head = c>>3
    int hd = c >> 3;
    int e0 = rowptr[n], e1 = rowptr[n + 1];
    float ad = ad_[n * 4 + hd];
    float m = -INFINITY, s = 0.f;
    float4 acc = {0.f, 0.f, 0.f, 0.f};
    int e = e0;
    for (; e + 3 < e1; e += 4) {
        int s0 = csr_src[e], s1 = csr_src[e + 1], s2 = csr_src[e + 2], s3 = csr_src[e + 3];
        float a0 = as_[s0 * 4 + hd] + ad;
        float a1 = as_[s1 * 4 + hd] + ad;
        float a2 = as_[s2 * 4 + hd] + ad;
        float a3 = as_[s3 * 4 + hd] + ad;
        a0 = a0 >= 0.f ? a0 : 0.2f * a0;
        a1 = a1 >= 0.f ? a1 : 0.2f * a1;
        a2 = a2 >= 0.f ? a2 : 0.2f * a2;
        a3 = a3 >= 0.f ? a3 : 0.2f * a3;
        float pm = fmaxf(fmaxf(a0, a1), fmaxf(a2, a3));
        if (pm > m) {                              // one rescale per 4 edges
            float sc = __expf(m - pm);
            s *= sc; acc.x *= sc; acc.y *= sc; acc.z *= sc; acc.w *= sc;
            m = pm;
        }
        float ex0 = __expf(a0 - m), ex1 = __expf(a1 - m);
        float ex2 = __expf(a2 - m), ex3 = __expf(a3 - m);
        s += (ex0 + ex1) + (ex2 + ex3);
        ushort4 u0 = *(const ushort4*)&hb[(size_t)s0 * 128 + c * 4];
        ushort4 u1 = *(const ushort4*)&hb[(size_t)s1 * 128 + c * 4];
        ushort4 u2 = *(const ushort4*)&hb[(size_t)s2 * 128 + c * 4];
        ushort4 u3 = *(const ushort4*)&hb[(size_t)s3 * 128 + c * 4];
        acc.x = fmaf(bf2f(u0.x), ex0, acc.x); acc.y = fmaf(bf2f(u0.y), ex0, acc.y);
        acc.z = fmaf(bf2f(u0.z), ex0, acc.z); acc.w = fmaf(bf2f(u0.w), ex0, acc.w);
        acc.x = fmaf(bf2f(u1.x), ex1, acc.x); acc.y = fmaf(bf2f(u1.y), ex1, acc.y);
        acc.z = fmaf(bf2f(u1.z), ex1, acc.z); acc.w = fmaf(bf2f(u1.w), ex1, acc.w);
        acc.x = fmaf(bf2f(u2.x), ex2, acc.x); acc.y = fmaf(bf2f(u2.y), ex2, acc.y);
        acc.z = fmaf(bf2f(u2.z), ex2, acc.z); acc.w = fmaf(bf2f(u2.w), ex2, acc.w);
        acc.x = fmaf(bf2f(u3.x), ex3, acc.x); acc.y = fmaf(bf2f(u3.y), ex3, acc.y);
        acc.z = fmaf(bf2f(u3.z), ex3, acc.z); acc.w = fmaf(bf2f(u3.w), ex3, acc.w);
    }
    for (; e < e1; ++e) {
        int s0 = csr_src[e];
        float a = as_[s0 * 4 + hd] + ad;
        a = a >= 0.f ? a : 0.2f * a;
        if (a > m) {
            float sc = __expf(m - a);
            s *= sc; acc.x *= sc; acc.y *= sc; acc.z *= sc; acc.w *= sc;
            m = a;
        }
        float ex = __expf(a - m);
        s += ex;
        ushort4 u = *(const ushort4*)&hb[(size_t)s0 * 128 + c * 4];
        acc.x = fmaf(bf2f(u.x), ex, acc.x); acc.y = fmaf(bf2f(u.y), ex, acc.y);
        acc.z = fmaf(bf2f(u.z), ex, acc.z); acc.w = fmaf(bf2f(u.w), ex, acc.w);
    }
    float inv = 1.0f / (s + 1e-16f);
    float rx = acc.x * inv + gb[c * 4 + 0];
    float ry = acc.y * inv + gb[c * 4 + 1];
    float rz = acc.z * inv + gb[c * 4 + 2];
    float rw = acc.w * inv + gb[c * 4 + 3];
    rx = rx > 0.f ? rx : expm1f(rx);
    ry = ry > 0.f ? ry : expm1f(ry);
    rz = rz > 0.f ? rz : expm1f(rz);
    rw = rw > 0.f ? rw : expm1f(rw);
    ushort4 o;
    o.x = f2bf(rx); o.y = f2bf(ry); o.z = f2bf(rz); o.w = f2bf(rw);
    *(ushort4*)&outb[(size_t)n * 128 + c * 4] = o;
}

// classifier: [N,256] @ [256,5] + b   (f32)
__global__ void cls_k(const float* __restrict__ h, const float* __restrict__ W,
                      const float* __restrict__ b, float* __restrict__ out) {
    __shared__ float sW[256 * 5];
    for (int i = threadIdx.x; i < 1280; i += TPB) sW[i] = W[i];
    __syncthreads();
    int n = blockIdx.x * TPB + threadIdx.x;
    if (n >= N_NODES) return;
    const float4* row = (const float4*)(h + (size_t)n * 256);
    float acc[5] = {0.f, 0.f, 0.f, 0.f, 0.f};
    for (int k4 = 0; k4 < 64; ++k4) {
        float4 v = row[k4];
        const float* w = &sW[k4 * 4 * 5];
#pragma unroll
        for (int c = 0; c < 5; ++c) acc[c] = fmaf(v.x, w[c], acc[c]);
#pragma unroll
        for (int c = 0; c < 5; ++c) acc[c] = fmaf(v.y, w[5 + c], acc[c]);
#pragma unroll
        for (int c = 0; c < 5; ++c) acc[c] = fmaf(v.z, w[10 + c], acc[c]);
#pragma unroll
        for (int c = 0; c < 5; ++c) acc[c] = fmaf(v.w, w[15 + c], acc[c]);
    }
#pragma unroll
    for (int c = 0; c < 5; ++c) out[(size_t)n * 5 + c] = acc[c] + b[c];
}

extern "C" void kernel_launch(void* const* d_in, const int* in_sizes, int n_in,
                              void* d_out, int out_size, void* d_ws, size_t ws_size,
                              hipStream_t stream) {
    const float* x    = (const float*)d_in[0];
    const int*   ei   = (const int*)d_in[1];
    const float* s1Wl = (const float*)d_in[2];
    const float* s1Wr = (const float*)d_in[3];
    const float* s1b  = (const float*)d_in[4];
    const float* gW   = (const float*)d_in[5];
    const float* gas  = (const float*)d_in[6];
    const float* gad  = (const float*)d_in[7];
    const float* gb   = (const float*)d_in[8];
    const float* s2Wl = (const float*)d_in[9];
    const float* s2Wr = (const float*)d_in[10];
    const float* s2b  = (const float*)d_in[11];
    const float* clsW = (const float*)d_in[12];
    const float* clsb = (const float*)d_in[13];
    float* out = (float*)d_out;
    const int* src = ei;            // edge_index[0]
    const int* dst = ei + N_EDGES;  // edge_index[1]

    // ---- workspace layout ----
    float* ws  = (float*)d_ws;
    float* A    = ws;                                 // N*256 f32 (h3 for cls)
    float* M20  = A + (size_t)N_NODES * 256;          // N*20 f32 (sage1 mean)
    float* as_  = M20 + (size_t)N_NODES * 20;         // N*4
    float* ad_  = as_ + N_NODES * 4;                  // N*4
    int* deg     = (int*)(ad_ + N_NODES * 4);         // N
    int* bsum    = deg + N_NODES;                     // 256
    int* rowptr  = bsum + 256;                        // N+1
    int* csr_src = rowptr + N_NODES + 1;              // E
    unsigned short* Wt1 = (unsigned short*)(csr_src + N_EDGES);  // 256*64
    unsigned short* Wt2 = Wt1 + 256 * 64;                        // 128*256
    unsigned short* Wt3 = Wt2 + 128 * 256;                       // 256*256
    unsigned short* Ab  = Wt3 + 256 * 256;                       // N*256 bf16 (h1)
    unsigned short* Cb  = Ab + (size_t)N_NODES * 256;            // N*128 bf16 (gat h)
    unsigned short* Db  = Cb + (size_t)N_NODES * 128;            // N*128 bf16 (gat out)
    unsigned short* Mb  = Db + (size_t)N_NODES * 128;            // N*128 bf16 (sage2 mean)

    const int MB = (N_NODES + 127) / 128;             // 391 row-blocks

    // ---- weights (1 launch) ----
    wt_all_k<<<(114688 + TPB - 1) / TPB, TPB, 0, stream>>>(s1Wl, s1Wr, gW, s2Wl, s2Wr,
                                                           Wt1, Wt2, Wt3);

    // ---- CSR build ----
    hipMemsetAsync(deg, 0, N_NODES * sizeof(int), stream);
    hist_k<<<(N_EDGES + TPB - 1) / TPB, TPB, 0, stream>>>(dst, deg);
    scan1_k<<<NCHUNK, 256, 0, stream>>>(deg, rowptr, bsum);
    scan2_k<<<1, 256, 0, stream>>>(bsum);
    scan3_k<<<NCHUNK, 256, 0, stream>>>(rowptr, bsum);
    fill_k<<<(N_EDGES + TPB - 1) / TPB, TPB, 0, stream>>>(src, dst, rowptr, deg, csr_src);

    // ---- SAGE1: Ab = bf16(relu([mean(x)|x] @ Wt1 + b)), K=40 (Kp=64) ----
    gm20_k<<<(N_NODES + 7) / 8, 256, 0, stream>>>(rowptr, csr_src, x, M20);
    gemm_mfma<1, 1><<<dim3(2, MB), 256, 0, stream>>>(M20, 20, x, 20, Wt1, 64, s1b,
                                                     nullptr, Ab, 256);

    // ---- GAT: Cb = bf16(Ab @ Wt2), K=256; scores; fused gather -> Db ----
    gemm_mfma_bf<0, 1><<<dim3(1, MB), 256, 0, stream>>>(Ab, 256, nullptr, 0, Wt2, 256,
                                                        nullptr, nullptr, Cb, 128);
    att_scores_bf<<<(N_NODES * 4 + TPB - 1) / TPB, TPB, 0, stream>>>(Cb, gas, gad, as_, ad_);
    gat_gather_bf<<<N_NODES / 8, 256, 0, stream>>>(rowptr, csr_src, Cb, as_, ad_, gb, Db);

    // ---- SAGE2: A = relu([mean(Db)|Db] @ Wt3 + b), K=256, f32 out ----
    gather_mean_bf<<<N_NODES / 8, 256, 0, stream>>>(rowptr, csr_src, Db, Mb);
    gemm_mfma_bf<1, 0><<<dim3(2, MB), 256, 0, stream>>>(Mb, 128, Db, 128, Wt3, 256, s2b,
                                                        A, nullptr, 256);

    // ---- classifier ----
    cls_k<<<(N_NODES + TPB - 1) / TPB, TPB, 0, stream>>>(A, clsW, clsb, out);
}